// Round 1
// baseline (4458.045 us; speedup 1.0000x reference)
//
#include <hip/hip_runtime.h>
#include <hip/hip_bf16.h>

// Problem constants (fixed by the reference file)
#define DIN   128
#define HID2  64
#define NCLS  10
#define NGRAPH 128

__device__ __forceinline__ void atomAddF(float* p, float v) {
    unsafeAtomicAdd(p, v);   // global_atomic_add_f32 on gfx950
}

// ---------- K0: W12 = lin1_w @ conv1_w ; c1preb = lin1_b @ conv1_w ----------
// grid 129 blocks x 128 threads. Block 128 computes the bias row.
__global__ __launch_bounds__(128) void k_w12(const float* __restrict__ lw,
                                             const float* __restrict__ lb,
                                             const float* __restrict__ cw,
                                             float* __restrict__ W12,
                                             float* __restrict__ c1preb) {
    int i = blockIdx.x, j = threadIdx.x;
    const float* arow = (i < 128) ? (lw + i * 128) : lb;
    float acc = 0.f;
#pragma unroll 8
    for (int k = 0; k < 128; ++k) acc += arow[k] * cw[k * 128 + j];
    if (i < 128) W12[i * 128 + j] = acc;
    else         c1preb[j] = acc;
}

// ---------- degree / dis ----------
__global__ __launch_bounds__(256) void k_fill1(float* p, int n) {
    int i = blockIdx.x * 256 + threadIdx.x;
    if (i < n) p[i] = 1.0f;           // self-loop contributes 1 to every degree
}
__global__ __launch_bounds__(256) void k_zero(float* p, int n) {
    int i = blockIdx.x * 256 + threadIdx.x;
    if (i < n) p[i] = 0.0f;
}
__global__ __launch_bounds__(256) void k_degE(const int* __restrict__ dst, float* deg, int E) {
    int e = blockIdx.x * 256 + threadIdx.x;
    if (e < E) atomAddF(&deg[dst[e]], 1.0f);
}
__global__ __launch_bounds__(256) void k_rsqrt(float* p, int n) {
    int i = blockIdx.x * 256 + threadIdx.x;
    if (i < n) p[i] = rsqrtf(p[i]);   // deg >= 1 always (self-loops)
}

// ---------- tiled fp32 GEMM: out[M x NCOL] = f(A[M x 128]) @ W[128 x NCOL] (+bias) ----------
// f = identity, or dropout(p=.5, mask=du>=.5, scale 2) followed by relu when MASK.
template <int NCOL, bool MASK>
__global__ __launch_bounds__(256) void k_gemm(const float* __restrict__ A,
                                              const float* __restrict__ W,
                                              const float* __restrict__ bias,
                                              const float* __restrict__ du,
                                              float* __restrict__ out, int M) {
    constexpr int CG = NCOL / 4;        // column groups (float4)
    constexpr int RSTRIDE = 256 / CG;   // 8 (N=128) or 16 (N=64)
    constexpr int RPT = 64 / RSTRIDE;   // rows per thread: 8 or 4
    __shared__ float As[64][33];        // 32-wide K chunk, +1 pad

    const int tid = threadIdx.x;
    const int cg = tid % CG;
    const int ry = tid / CG;
    const int row0 = blockIdx.x * 64;

    float4 acc[RPT];
#pragma unroll
    for (int j = 0; j < RPT; ++j) acc[j] = make_float4(0.f, 0.f, 0.f, 0.f);

    for (int kk = 0; kk < 128; kk += 32) {
        __syncthreads();
        // stage A tile: 64 rows x 32 cols = 512 float4, 2 per thread
#pragma unroll
        for (int t = tid; t < 512; t += 256) {
            int r = t >> 3;            // row in tile
            int c4 = t & 7;            // float4 within 32-col chunk
            int gr = row0 + r;
            float4 v = make_float4(0.f, 0.f, 0.f, 0.f);
            if (gr < M) {
                v = *(const float4*)(A + (size_t)gr * 128 + kk + c4 * 4);
                if (MASK) {
                    float4 u = *(const float4*)(du + (size_t)gr * 128 + kk + c4 * 4);
                    v.x = (u.x >= 0.5f) ? 2.f * fmaxf(v.x, 0.f) : 0.f;
                    v.y = (u.y >= 0.5f) ? 2.f * fmaxf(v.y, 0.f) : 0.f;
                    v.z = (u.z >= 0.5f) ? 2.f * fmaxf(v.z, 0.f) : 0.f;
                    v.w = (u.w >= 0.5f) ? 2.f * fmaxf(v.w, 0.f) : 0.f;
                }
            }
            As[r][c4 * 4 + 0] = v.x;
            As[r][c4 * 4 + 1] = v.y;
            As[r][c4 * 4 + 2] = v.z;
            As[r][c4 * 4 + 3] = v.w;
        }
        __syncthreads();
#pragma unroll 4
        for (int k = 0; k < 32; ++k) {
            const float4 wv = *(const float4*)(W + (size_t)(kk + k) * NCOL + cg * 4);
            float a[RPT];
#pragma unroll
            for (int j = 0; j < RPT; ++j) a[j] = As[ry + RSTRIDE * j][k];
#pragma unroll
            for (int j = 0; j < RPT; ++j) {
                acc[j].x = fmaf(a[j], wv.x, acc[j].x);
                acc[j].y = fmaf(a[j], wv.y, acc[j].y);
                acc[j].z = fmaf(a[j], wv.z, acc[j].z);
                acc[j].w = fmaf(a[j], wv.w, acc[j].w);
            }
        }
    }
    float4 b4 = make_float4(0.f, 0.f, 0.f, 0.f);
    if (bias) b4 = *(const float4*)(bias + cg * 4);
#pragma unroll
    for (int j = 0; j < RPT; ++j) {
        int gr = row0 + ry + RSTRIDE * j;
        if (gr < M) {
            float4 r;
            r.x = acc[j].x + b4.x; r.y = acc[j].y + b4.y;
            r.z = acc[j].z + b4.z; r.w = acc[j].w + b4.w;
            *(float4*)(out + (size_t)gr * NCOL + cg * 4) = r;
        }
    }
}

// ---------- init aggregation output: out[i] = bias + dis[i]^2 * h[i] (self loop) ----------
template <int NCOL>
__global__ __launch_bounds__(256) void k_init_out(const float* __restrict__ h,
                                                  const float* __restrict__ bias,
                                                  const float* __restrict__ dis,
                                                  float* __restrict__ out, int n) {
    int tid = blockIdx.x * 256 + threadIdx.x;
    constexpr int C4 = NCOL / 4;
    if (tid >= n * C4) return;
    int i = tid / C4, c = tid % C4;
    float d2 = dis[i] * dis[i];
    float4 v = ((const float4*)h)[tid];
    float4 b = ((const float4*)bias)[c];
    float4 r;
    r.x = fmaf(d2, v.x, b.x); r.y = fmaf(d2, v.y, b.y);
    r.z = fmaf(d2, v.z, b.z); r.w = fmaf(d2, v.w, b.w);
    ((float4*)out)[tid] = r;
}

// ---------- edge scatter: out[dst] += dis[src]*dis[dst] * h[src] ----------
template <int NCOL>
__global__ __launch_bounds__(256) void k_scatter(const float* __restrict__ h,
                                                 const int* __restrict__ src,
                                                 const int* __restrict__ dst,
                                                 const float* __restrict__ dis,
                                                 float* __restrict__ out, int E) {
    constexpr int LPE = NCOL / 4;    // lanes per edge
    int tid = blockIdx.x * 256 + threadIdx.x;
    int e = tid / LPE;
    int l = tid % LPE;
    if (e >= E) return;
    int s = src[e], d = dst[e];
    float nrm = dis[s] * dis[d];
    float4 v = *(const float4*)(h + (size_t)s * NCOL + l * 4);
    float* o = out + (size_t)d * NCOL + l * 4;
    atomAddF(o + 0, v.x * nrm);
    atomAddF(o + 1, v.y * nrm);
    atomAddF(o + 2, v.z * nrm);
    atomAddF(o + 3, v.w * nrm);
}

// ---------- pooling: sorted-batch sequential accumulation, flush on graph change ----------
__global__ __launch_bounds__(256) void k_pool(const float* __restrict__ h,  // [n x 64]
                                              const int* __restrict__ batch,
                                              float* __restrict__ sums,     // [128 x 64]
                                              float* __restrict__ cnt,      // [128]
                                              int n) {
    int gid = (blockIdx.x * 256 + threadIdx.x) / 64;   // group of 64 lanes
    int f = threadIdx.x % 64;
    int ngroups = gridDim.x * 4;
    int per = (n + ngroups - 1) / ngroups;
    int start = gid * per;
    int end = min(n, start + per);
    if (start >= end) return;
    int cg = batch[start];
    float acc = 0.f;
    int count = 0;
    for (int i = start; i < end; ++i) {
        int b = batch[i];
        if (b != cg) {
            atomAddF(&sums[cg * 64 + f], acc);
            if (f == 0) atomAddF(&cnt[cg], (float)count);
            acc = 0.f; count = 0; cg = b;
        }
        acc += h[(size_t)i * 64 + f];
        ++count;
    }
    atomAddF(&sums[cg * 64 + f], acc);
    if (f == 0) atomAddF(&cnt[cg], (float)count);
}

// ---------- final: out = (sums/max(cnt,1)) @ lin2_w + lin2_b ----------
__global__ __launch_bounds__(64) void k_final(const float* __restrict__ sums,
                                              const float* __restrict__ cnt,
                                              const float* __restrict__ w,   // [64 x 10]
                                              const float* __restrict__ b,   // [10]
                                              float* __restrict__ out) {
    int g = blockIdx.x, f = threadIdx.x;   // 64 threads
    float c = fmaxf(cnt[g], 1.0f);
    float p = sums[g * 64 + f] / c;
#pragma unroll
    for (int cls = 0; cls < NCLS; ++cls) {
        float v = p * w[f * 10 + cls];
#pragma unroll
        for (int o = 32; o > 0; o >>= 1) v += __shfl_down(v, o);
        if (f == 0) out[g * 10 + cls] = v + b[cls];
    }
}

extern "C" void kernel_launch(void* const* d_in, const int* in_sizes, int n_in,
                              void* d_out, int out_size, void* d_ws, size_t ws_size,
                              hipStream_t stream) {
    const float* x       = (const float*)d_in[0];
    const int*   ei      = (const int*)d_in[1];
    const int*   batch   = (const int*)d_in[2];
    const float* drop_u  = (const float*)d_in[4];
    const float* lin1_w  = (const float*)d_in[5];
    const float* lin1_b  = (const float*)d_in[6];
    const float* conv1_w = (const float*)d_in[7];
    const float* conv1_b = (const float*)d_in[8];
    const float* conv2_w = (const float*)d_in[9];
    const float* conv2_b = (const float*)d_in[10];
    const float* lin2_w  = (const float*)d_in[11];
    const float* lin2_b  = (const float*)d_in[12];
    float* out = (float*)d_out;

    const int N = in_sizes[0] / DIN;        // 100000
    const int E = in_sizes[1] / 2;          // 1600000
    const int* src = ei;
    const int* dst = ei + E;

    // workspace layout (floats)
    float* ws    = (float*)d_ws;
    float* h1    = ws;                              // N*128  (reused as h2: N*64)
    float* out1  = ws + (size_t)N * 128;            // N*128  (reused as out2: N*64)
    float* dis   = ws + (size_t)2 * N * 128;        // N
    float* W12   = dis + N;                         // 16384
    float* c1pb  = W12 + 16384;                     // 128
    float* sums  = c1pb + 128;                      // 128*64
    float* cnt   = sums + NGRAPH * 64;              // 128
    float* h2    = h1;
    float* out2  = out1;

    // fused weight + pre-aggregation bias
    k_w12<<<129, 128, 0, stream>>>(lin1_w, lin1_b, conv1_w, W12, c1pb);

    // degrees -> dis = deg^{-1/2}
    k_fill1<<<(N + 255) / 256, 256, 0, stream>>>(dis, N);
    k_degE<<<(E + 255) / 256, 256, 0, stream>>>(dst, dis, E);
    k_rsqrt<<<(N + 255) / 256, 256, 0, stream>>>(dis, N);

    // h1 = x @ W12 + c1pb
    const int gemmGrid = (N + 63) / 64;
    k_gemm<128, false><<<gemmGrid, 256, 0, stream>>>(x, W12, c1pb, nullptr, h1, N);

    // conv1 aggregation
    k_init_out<128><<<((size_t)N * 32 + 255) / 256, 256, 0, stream>>>(h1, conv1_b, dis, out1, N);
    k_scatter<128><<<((size_t)E * 32 + 255) / 256, 256, 0, stream>>>(h1, src, dst, dis, out1, E);

    // h2 = relu(dropout(out1)) @ conv2_w   (no bias here; conv2_b added post-agg)
    k_gemm<64, true><<<gemmGrid, 256, 0, stream>>>(out1, conv2_w, nullptr, drop_u, h2, N);

    // conv2 aggregation
    k_init_out<64><<<((size_t)N * 16 + 255) / 256, 256, 0, stream>>>(h2, conv2_b, dis, out2, N);
    k_scatter<64><<<((size_t)E * 16 + 255) / 256, 256, 0, stream>>>(h2, src, dst, dis, out2, E);

    // pooled mean + classifier
    k_zero<<<(NGRAPH * 64 + NGRAPH + 255) / 256, 256, 0, stream>>>(sums, NGRAPH * 64 + NGRAPH);
    k_pool<<<128, 256, 0, stream>>>(out2, batch, sums, cnt, N);
    k_final<<<NGRAPH, 64, 0, stream>>>(sums, cnt, lin2_w, lin2_b, out);
}

// Round 2
// 924.628 us; speedup vs baseline: 4.8214x; 4.8214x over previous
//
#include <hip/hip_runtime.h>
#include <hip/hip_bf16.h>

// Problem constants (fixed by the reference file)
#define DIN   128
#define HID2  64
#define NCLS  10
#define NGRAPH 128

__device__ __forceinline__ void atomAddF(float* p, float v) {
    unsafeAtomicAdd(p, v);   // global_atomic_add_f32 on gfx950
}

// ---------- K0: W12 = lin1_w @ conv1_w ; c1preb = lin1_b @ conv1_w ----------
__global__ __launch_bounds__(128) void k_w12(const float* __restrict__ lw,
                                             const float* __restrict__ lb,
                                             const float* __restrict__ cw,
                                             float* __restrict__ W12,
                                             float* __restrict__ c1preb) {
    int i = blockIdx.x, j = threadIdx.x;
    const float* arow = (i < 128) ? (lw + i * 128) : lb;
    float acc = 0.f;
#pragma unroll 8
    for (int k = 0; k < 128; ++k) acc += arow[k] * cw[k * 128 + j];
    if (i < 128) W12[i * 128 + j] = acc;
    else         c1preb[j] = acc;
}

// ---------- CSR build ----------
__global__ __launch_bounds__(256) void k_zeroi(int* p, int n) {
    int i = blockIdx.x * 256 + threadIdx.x;
    if (i < n) p[i] = 0;
}
__global__ __launch_bounds__(256) void k_zero(float* p, int n) {
    int i = blockIdx.x * 256 + threadIdx.x;
    if (i < n) p[i] = 0.0f;
}
__global__ __launch_bounds__(256) void k_count(const int* __restrict__ dst, int* cnt, int E) {
    int e = blockIdx.x * 256 + threadIdx.x;
    if (e < E) atomicAdd(&cnt[dst[e]], 1);
}
// dis[i] = rsqrt(cnt[i] + 1)  (self-loop adds 1 to every degree)
__global__ __launch_bounds__(256) void k_dis(const int* __restrict__ cnt, float* dis, int n) {
    int i = blockIdx.x * 256 + threadIdx.x;
    if (i < n) dis[i] = rsqrtf((float)(cnt[i] + 1));
}
// single-block exclusive scan of cnt[0..n) -> row_start[0..n], cursor copy
__global__ __launch_bounds__(1024) void k_scan(const int* __restrict__ cnt,
                                               int* __restrict__ row_start,
                                               int* __restrict__ cursor, int n) {
    __shared__ int part[1024];
    const int t = threadIdx.x;
    const int CH = (n + 1023) / 1024;
    const int beg = t * CH, end = min(n, beg + CH);
    int s = 0;
    for (int i = beg; i < end; ++i) s += cnt[i];
    part[t] = s;
    __syncthreads();
    for (int off = 1; off < 1024; off <<= 1) {
        int v = (t >= off) ? part[t - off] : 0;
        __syncthreads();
        part[t] += v;
        __syncthreads();
    }
    int excl = (t == 0) ? 0 : part[t - 1];
    for (int i = beg; i < end; ++i) {
        row_start[i] = excl;
        cursor[i] = excl;
        excl += cnt[i];
    }
    if (t == 1023) row_start[n] = part[1023];
}
__global__ __launch_bounds__(256) void k_fill(const int* __restrict__ src,
                                              const int* __restrict__ dst,
                                              int* __restrict__ cursor,
                                              int* __restrict__ col, int E) {
    int e = blockIdx.x * 256 + threadIdx.x;
    if (e >= E) return;
    int pos = atomicAdd(&cursor[dst[e]], 1);
    col[pos] = src[e];
}

// ---------- tiled fp32 GEMM: out[M x NCOL] = f(A[M x 128]) @ W[128 x NCOL] (+bias) ----------
template <int NCOL, bool MASK>
__global__ __launch_bounds__(256) void k_gemm(const float* __restrict__ A,
                                              const float* __restrict__ W,
                                              const float* __restrict__ bias,
                                              const float* __restrict__ du,
                                              float* __restrict__ out, int M) {
    constexpr int CG = NCOL / 4;
    constexpr int RSTRIDE = 256 / CG;
    constexpr int RPT = 64 / RSTRIDE;
    __shared__ float As[64][33];

    const int tid = threadIdx.x;
    const int cg = tid % CG;
    const int ry = tid / CG;
    const int row0 = blockIdx.x * 64;

    float4 acc[RPT];
#pragma unroll
    for (int j = 0; j < RPT; ++j) acc[j] = make_float4(0.f, 0.f, 0.f, 0.f);

    for (int kk = 0; kk < 128; kk += 32) {
        __syncthreads();
#pragma unroll
        for (int t = tid; t < 512; t += 256) {
            int r = t >> 3;
            int c4 = t & 7;
            int gr = row0 + r;
            float4 v = make_float4(0.f, 0.f, 0.f, 0.f);
            if (gr < M) {
                v = *(const float4*)(A + (size_t)gr * 128 + kk + c4 * 4);
                if (MASK) {
                    float4 u = *(const float4*)(du + (size_t)gr * 128 + kk + c4 * 4);
                    v.x = (u.x >= 0.5f) ? 2.f * fmaxf(v.x, 0.f) : 0.f;
                    v.y = (u.y >= 0.5f) ? 2.f * fmaxf(v.y, 0.f) : 0.f;
                    v.z = (u.z >= 0.5f) ? 2.f * fmaxf(v.z, 0.f) : 0.f;
                    v.w = (u.w >= 0.5f) ? 2.f * fmaxf(v.w, 0.f) : 0.f;
                }
            }
            As[r][c4 * 4 + 0] = v.x;
            As[r][c4 * 4 + 1] = v.y;
            As[r][c4 * 4 + 2] = v.z;
            As[r][c4 * 4 + 3] = v.w;
        }
        __syncthreads();
#pragma unroll 4
        for (int k = 0; k < 32; ++k) {
            const float4 wv = *(const float4*)(W + (size_t)(kk + k) * NCOL + cg * 4);
            float a[RPT];
#pragma unroll
            for (int j = 0; j < RPT; ++j) a[j] = As[ry + RSTRIDE * j][k];
#pragma unroll
            for (int j = 0; j < RPT; ++j) {
                acc[j].x = fmaf(a[j], wv.x, acc[j].x);
                acc[j].y = fmaf(a[j], wv.y, acc[j].y);
                acc[j].z = fmaf(a[j], wv.z, acc[j].z);
                acc[j].w = fmaf(a[j], wv.w, acc[j].w);
            }
        }
    }
    float4 b4 = make_float4(0.f, 0.f, 0.f, 0.f);
    if (bias) b4 = *(const float4*)(bias + cg * 4);
#pragma unroll
    for (int j = 0; j < RPT; ++j) {
        int gr = row0 + ry + RSTRIDE * j;
        if (gr < M) {
            float4 r;
            r.x = acc[j].x + b4.x; r.y = acc[j].y + b4.y;
            r.z = acc[j].z + b4.z; r.w = acc[j].w + b4.w;
            *(float4*)(out + (size_t)gr * NCOL + cg * 4) = r;
        }
    }
}

// ---------- CSR gather: out[d] = bias + dis_d*(dis_d*h[d] + sum_{s in row(d)} dis_s*h[s]) ----------
template <int NCOL>
__global__ __launch_bounds__(256) void k_gather(const float* __restrict__ h,
                                                const int* __restrict__ row_start,
                                                const int* __restrict__ col,
                                                const float* __restrict__ dis,
                                                const float* __restrict__ bias,
                                                float* __restrict__ out, int n) {
    constexpr int LPN = NCOL / 4;   // lanes per node (float4 each)
    const int node = (blockIdx.x * 256 + threadIdx.x) / LPN;
    const int l = threadIdx.x % LPN;
    if (node >= n) return;

    const float dn = dis[node];
    const size_t coff = (size_t)l * 4;
    float4 hv = *(const float4*)(h + (size_t)node * NCOL + coff);
    float4 acc;
    acc.x = dn * hv.x; acc.y = dn * hv.y; acc.z = dn * hv.z; acc.w = dn * hv.w;

    const int beg = row_start[node], end = row_start[node + 1];
    for (int j = beg; j < end; ++j) {
        const int s = col[j];
        const float ds = dis[s];
        const float4 v = *(const float4*)(h + (size_t)s * NCOL + coff);
        acc.x = fmaf(ds, v.x, acc.x);
        acc.y = fmaf(ds, v.y, acc.y);
        acc.z = fmaf(ds, v.z, acc.z);
        acc.w = fmaf(ds, v.w, acc.w);
    }
    const float4 b4 = *(const float4*)(bias + coff);
    float4 r;
    r.x = fmaf(dn, acc.x, b4.x);
    r.y = fmaf(dn, acc.y, b4.y);
    r.z = fmaf(dn, acc.z, b4.z);
    r.w = fmaf(dn, acc.w, b4.w);
    *(float4*)(out + (size_t)node * NCOL + coff) = r;
}

// ---------- pooling: sorted-batch sequential accumulation ----------
__global__ __launch_bounds__(256) void k_pool(const float* __restrict__ h,
                                              const int* __restrict__ batch,
                                              float* __restrict__ sums,
                                              float* __restrict__ cnt,
                                              int n) {
    int gid = (blockIdx.x * 256 + threadIdx.x) / 64;
    int f = threadIdx.x % 64;
    int ngroups = gridDim.x * 4;
    int per = (n + ngroups - 1) / ngroups;
    int start = gid * per;
    int end = min(n, start + per);
    if (start >= end) return;
    int cg = batch[start];
    float acc = 0.f;
    int count = 0;
    for (int i = start; i < end; ++i) {
        int b = batch[i];
        if (b != cg) {
            atomAddF(&sums[cg * 64 + f], acc);
            if (f == 0) atomAddF(&cnt[cg], (float)count);
            acc = 0.f; count = 0; cg = b;
        }
        acc += h[(size_t)i * 64 + f];
        ++count;
    }
    atomAddF(&sums[cg * 64 + f], acc);
    if (f == 0) atomAddF(&cnt[cg], (float)count);
}

// ---------- final: out = (sums/max(cnt,1)) @ lin2_w + lin2_b ----------
__global__ __launch_bounds__(64) void k_final(const float* __restrict__ sums,
                                              const float* __restrict__ cnt,
                                              const float* __restrict__ w,
                                              const float* __restrict__ b,
                                              float* __restrict__ out) {
    int g = blockIdx.x, f = threadIdx.x;
    float c = fmaxf(cnt[g], 1.0f);
    float p = sums[g * 64 + f] / c;
#pragma unroll
    for (int cls = 0; cls < NCLS; ++cls) {
        float v = p * w[f * 10 + cls];
#pragma unroll
        for (int o = 32; o > 0; o >>= 1) v += __shfl_down(v, o);
        if (f == 0) out[g * 10 + cls] = v + b[cls];
    }
}

extern "C" void kernel_launch(void* const* d_in, const int* in_sizes, int n_in,
                              void* d_out, int out_size, void* d_ws, size_t ws_size,
                              hipStream_t stream) {
    const float* x       = (const float*)d_in[0];
    const int*   ei      = (const int*)d_in[1];
    const int*   batch   = (const int*)d_in[2];
    const float* drop_u  = (const float*)d_in[4];
    const float* lin1_w  = (const float*)d_in[5];
    const float* lin1_b  = (const float*)d_in[6];
    const float* conv1_w = (const float*)d_in[7];
    const float* conv1_b = (const float*)d_in[8];
    const float* conv2_w = (const float*)d_in[9];
    const float* conv2_b = (const float*)d_in[10];
    const float* lin2_w  = (const float*)d_in[11];
    const float* lin2_b  = (const float*)d_in[12];
    float* out = (float*)d_out;

    const int N = in_sizes[0] / DIN;        // 100000
    const int E = in_sizes[1] / 2;          // 1600000
    const int* src = ei;
    const int* dst = ei + E;

    // workspace layout
    float* ws    = (float*)d_ws;
    float* h1    = ws;                              // N*128  (reused as h2: N*64)
    float* out1  = ws + (size_t)N * 128;            // N*128  (reused as out2: N*64)
    float* dis   = ws + (size_t)2 * N * 128;        // N
    float* W12   = dis + N;                         // 16384
    float* c1pb  = W12 + 16384;                     // 128
    float* sums  = c1pb + 128;                      // 128*64
    float* cntp  = sums + NGRAPH * 64;              // 128
    int*   cnt   = (int*)(cntp + NGRAPH);           // N
    int*   row_start = cnt + N;                     // N+1
    int*   cursor    = row_start + N + 1;           // N
    int*   col       = cursor + N;                  // E
    float* h2    = h1;
    float* out2  = out1;

    // fused weight + pre-aggregation bias
    k_w12<<<129, 128, 0, stream>>>(lin1_w, lin1_b, conv1_w, W12, c1pb);

    // CSR build: histogram -> dis -> scan -> fill
    k_zeroi<<<(N + 255) / 256, 256, 0, stream>>>(cnt, N);
    k_count<<<(E + 255) / 256, 256, 0, stream>>>(dst, cnt, E);
    k_dis<<<(N + 255) / 256, 256, 0, stream>>>(cnt, dis, N);
    k_scan<<<1, 1024, 0, stream>>>(cnt, row_start, cursor, N);
    k_fill<<<(E + 255) / 256, 256, 0, stream>>>(src, dst, cursor, col, E);

    // h1 = x @ W12 + c1pb
    const int gemmGrid = (N + 63) / 64;
    k_gemm<128, false><<<gemmGrid, 256, 0, stream>>>(x, W12, c1pb, nullptr, h1, N);

    // conv1 aggregation (gather, bias+self-loop folded)
    k_gather<128><<<((size_t)N * 32 + 255) / 256, 256, 0, stream>>>(h1, row_start, col, dis, conv1_b, out1, N);

    // h2 = relu(dropout(out1)) @ conv2_w
    k_gemm<64, true><<<gemmGrid, 256, 0, stream>>>(out1, conv2_w, nullptr, drop_u, h2, N);

    // conv2 aggregation
    k_gather<64><<<((size_t)N * 16 + 255) / 256, 256, 0, stream>>>(h2, row_start, col, dis, conv2_b, out2, N);

    // pooled mean + classifier
    k_zero<<<(NGRAPH * 64 + NGRAPH + 255) / 256, 256, 0, stream>>>(sums, NGRAPH * 64 + NGRAPH);
    k_pool<<<128, 256, 0, stream>>>(out2, batch, sums, cntp, N);
    k_final<<<NGRAPH, 64, 0, stream>>>(sums, cntp, lin2_w, lin2_b, out);
}

// Round 3
// 717.060 us; speedup vs baseline: 6.2171x; 1.2895x over previous
//
#include <hip/hip_runtime.h>
#include <hip/hip_bf16.h>

// Problem constants (fixed by the reference file)
#define DIN   128
#define HID2  64
#define NCLS  10
#define NGRAPH 128
#define SCAN_CHUNK 1024   // elements per block in the 3-phase scan

__device__ __forceinline__ void atomAddF(float* p, float v) {
    unsafeAtomicAdd(p, v);   // global_atomic_add_f32 on gfx950
}

// ---------- K0: W12 = lin1_w @ conv1_w ; c1preb = lin1_b @ conv1_w ----------
__global__ __launch_bounds__(128) void k_w12(const float* __restrict__ lw,
                                             const float* __restrict__ lb,
                                             const float* __restrict__ cw,
                                             float* __restrict__ W12,
                                             float* __restrict__ c1preb) {
    int i = blockIdx.x, j = threadIdx.x;
    const float* arow = (i < 128) ? (lw + i * 128) : lb;
    float acc = 0.f;
#pragma unroll 8
    for (int k = 0; k < 128; ++k) acc += arow[k] * cw[k * 128 + j];
    if (i < 128) W12[i * 128 + j] = acc;
    else         c1preb[j] = acc;
}

// ---------- CSR build ----------
__global__ __launch_bounds__(256) void k_zeroi(int* p, int n) {
    int i = blockIdx.x * 256 + threadIdx.x;
    if (i < n) p[i] = 0;
}
__global__ __launch_bounds__(256) void k_zero(float* p, int n) {
    int i = blockIdx.x * 256 + threadIdx.x;
    if (i < n) p[i] = 0.0f;
}
__global__ __launch_bounds__(256) void k_count(const int* __restrict__ dst, int* cnt, int E) {
    int e = blockIdx.x * 256 + threadIdx.x;
    if (e < E) atomicAdd(&cnt[dst[e]], 1);
}
__global__ __launch_bounds__(256) void k_dis(const int* __restrict__ cnt, float* dis, int n) {
    int i = blockIdx.x * 256 + threadIdx.x;
    if (i < n) dis[i] = rsqrtf((float)(cnt[i] + 1));   // +1 self-loop
}

// --- 3-phase parallel exclusive scan of cnt[0..n) -> row_start[0..n] + cursor copy ---
// phase 1: per-block (1024-elem chunk) sums
__global__ __launch_bounds__(256) void k_scan_part(const int* __restrict__ cnt,
                                                   int* __restrict__ part, int n) {
    int base = blockIdx.x * SCAN_CHUNK + threadIdx.x * 4;
    int s = 0;
#pragma unroll
    for (int j = 0; j < 4; ++j) { int i = base + j; if (i < n) s += cnt[i]; }
#pragma unroll
    for (int o = 32; o > 0; o >>= 1) s += __shfl_down(s, o);
    __shared__ int wsum[4];
    if ((threadIdx.x & 63) == 0) wsum[threadIdx.x >> 6] = s;
    __syncthreads();
    if (threadIdx.x == 0) part[blockIdx.x] = wsum[0] + wsum[1] + wsum[2] + wsum[3];
}
// phase 2: exclusive-scan the (<=256) partials in one small block; write total
__global__ __launch_bounds__(256) void k_scan_mid(int* __restrict__ part,
                                                  int* __restrict__ row_start,
                                                  int B, int n) {
    __shared__ int sh[256];
    int t = threadIdx.x;
    int v = (t < B) ? part[t] : 0;
    sh[t] = v;
    __syncthreads();
    for (int off = 1; off < 256; off <<= 1) {
        int u = (t >= off) ? sh[t - off] : 0;
        __syncthreads();
        sh[t] += u;
        __syncthreads();
    }
    if (t < B) part[t] = sh[t] - v;          // exclusive prefix
    if (t == 255) row_start[n] = sh[255];    // grand total
}
// phase 3: local re-scan + block offset -> row_start / cursor
__global__ __launch_bounds__(256) void k_scan_fin(const int* __restrict__ cnt,
                                                  const int* __restrict__ part,
                                                  int* __restrict__ row_start,
                                                  int* __restrict__ cursor, int n) {
    __shared__ int sh[256];
    int t = threadIdx.x;
    int base = blockIdx.x * SCAN_CHUNK + t * 4;
    int c[4]; int s = 0;
#pragma unroll
    for (int j = 0; j < 4; ++j) { int i = base + j; c[j] = (i < n) ? cnt[i] : 0; s += c[j]; }
    sh[t] = s;
    __syncthreads();
    for (int off = 1; off < 256; off <<= 1) {
        int u = (t >= off) ? sh[t - off] : 0;
        __syncthreads();
        sh[t] += u;
        __syncthreads();
    }
    int excl = part[blockIdx.x] + sh[t] - s;
#pragma unroll
    for (int j = 0; j < 4; ++j) {
        int i = base + j;
        if (i < n) { row_start[i] = excl; cursor[i] = excl; }
        excl += c[j];
    }
}

__global__ __launch_bounds__(256) void k_fill(const int* __restrict__ src,
                                              const int* __restrict__ dst,
                                              int* __restrict__ cursor,
                                              int* __restrict__ col, int E) {
    int e = blockIdx.x * 256 + threadIdx.x;
    if (e >= E) return;
    int pos = atomicAdd(&cursor[dst[e]], 1);
    col[pos] = src[e];
}

// ---------- tiled fp32 GEMM: out[M x NCOL] = f(A[M x 128]) @ W[128 x NCOL] (+bias) ----------
template <int NCOL, bool MASK>
__global__ __launch_bounds__(256) void k_gemm(const float* __restrict__ A,
                                              const float* __restrict__ W,
                                              const float* __restrict__ bias,
                                              const float* __restrict__ du,
                                              float* __restrict__ out, int M) {
    constexpr int CG = NCOL / 4;
    constexpr int RSTRIDE = 256 / CG;
    constexpr int RPT = 64 / RSTRIDE;
    __shared__ float As[64][33];

    const int tid = threadIdx.x;
    const int cg = tid % CG;
    const int ry = tid / CG;
    const int row0 = blockIdx.x * 64;

    float4 acc[RPT];
#pragma unroll
    for (int j = 0; j < RPT; ++j) acc[j] = make_float4(0.f, 0.f, 0.f, 0.f);

    for (int kk = 0; kk < 128; kk += 32) {
        __syncthreads();
#pragma unroll
        for (int t = tid; t < 512; t += 256) {
            int r = t >> 3;
            int c4 = t & 7;
            int gr = row0 + r;
            float4 v = make_float4(0.f, 0.f, 0.f, 0.f);
            if (gr < M) {
                v = *(const float4*)(A + (size_t)gr * 128 + kk + c4 * 4);
                if (MASK) {
                    float4 u = *(const float4*)(du + (size_t)gr * 128 + kk + c4 * 4);
                    v.x = (u.x >= 0.5f) ? 2.f * fmaxf(v.x, 0.f) : 0.f;
                    v.y = (u.y >= 0.5f) ? 2.f * fmaxf(v.y, 0.f) : 0.f;
                    v.z = (u.z >= 0.5f) ? 2.f * fmaxf(v.z, 0.f) : 0.f;
                    v.w = (u.w >= 0.5f) ? 2.f * fmaxf(v.w, 0.f) : 0.f;
                }
            }
            As[r][c4 * 4 + 0] = v.x;
            As[r][c4 * 4 + 1] = v.y;
            As[r][c4 * 4 + 2] = v.z;
            As[r][c4 * 4 + 3] = v.w;
        }
        __syncthreads();
#pragma unroll 4
        for (int k = 0; k < 32; ++k) {
            const float4 wv = *(const float4*)(W + (size_t)(kk + k) * NCOL + cg * 4);
            float a[RPT];
#pragma unroll
            for (int j = 0; j < RPT; ++j) a[j] = As[ry + RSTRIDE * j][k];
#pragma unroll
            for (int j = 0; j < RPT; ++j) {
                acc[j].x = fmaf(a[j], wv.x, acc[j].x);
                acc[j].y = fmaf(a[j], wv.y, acc[j].y);
                acc[j].z = fmaf(a[j], wv.z, acc[j].z);
                acc[j].w = fmaf(a[j], wv.w, acc[j].w);
            }
        }
    }
    float4 b4 = make_float4(0.f, 0.f, 0.f, 0.f);
    if (bias) b4 = *(const float4*)(bias + cg * 4);
#pragma unroll
    for (int j = 0; j < RPT; ++j) {
        int gr = row0 + ry + RSTRIDE * j;
        if (gr < M) {
            float4 r;
            r.x = acc[j].x + b4.x; r.y = acc[j].y + b4.y;
            r.z = acc[j].z + b4.z; r.w = acc[j].w + b4.w;
            *(float4*)(out + (size_t)gr * NCOL + cg * 4) = r;
        }
    }
}

// ---------- CSR gather: out[d] = bias + dis_d*(dis_d*h[d] + sum_{s in row(d)} dis_s*h[s]) ----------
template <int NCOL>
__global__ __launch_bounds__(256) void k_gather(const float* __restrict__ h,
                                                const int* __restrict__ row_start,
                                                const int* __restrict__ col,
                                                const float* __restrict__ dis,
                                                const float* __restrict__ bias,
                                                float* __restrict__ out, int n) {
    constexpr int LPN = NCOL / 4;
    const int node = (blockIdx.x * 256 + threadIdx.x) / LPN;
    const int l = threadIdx.x % LPN;
    if (node >= n) return;

    const float dn = dis[node];
    const size_t coff = (size_t)l * 4;
    float4 hv = *(const float4*)(h + (size_t)node * NCOL + coff);
    float4 acc;
    acc.x = dn * hv.x; acc.y = dn * hv.y; acc.z = dn * hv.z; acc.w = dn * hv.w;

    const int beg = row_start[node], end = row_start[node + 1];
    for (int j = beg; j < end; ++j) {
        const int s = col[j];
        const float ds = dis[s];
        const float4 v = *(const float4*)(h + (size_t)s * NCOL + coff);
        acc.x = fmaf(ds, v.x, acc.x);
        acc.y = fmaf(ds, v.y, acc.y);
        acc.z = fmaf(ds, v.z, acc.z);
        acc.w = fmaf(ds, v.w, acc.w);
    }
    const float4 b4 = *(const float4*)(bias + coff);
    float4 r;
    r.x = fmaf(dn, acc.x, b4.x);
    r.y = fmaf(dn, acc.y, b4.y);
    r.z = fmaf(dn, acc.z, b4.z);
    r.w = fmaf(dn, acc.w, b4.w);
    *(float4*)(out + (size_t)node * NCOL + coff) = r;
}

// ---------- pooling: sorted-batch sequential accumulation ----------
__global__ __launch_bounds__(256) void k_pool(const float* __restrict__ h,
                                              const int* __restrict__ batch,
                                              float* __restrict__ sums,
                                              float* __restrict__ cnt,
                                              int n) {
    int gid = (blockIdx.x * 256 + threadIdx.x) / 64;
    int f = threadIdx.x % 64;
    int ngroups = gridDim.x * 4;
    int per = (n + ngroups - 1) / ngroups;
    int start = gid * per;
    int end = min(n, start + per);
    if (start >= end) return;
    int cg = batch[start];
    float acc = 0.f;
    int count = 0;
    for (int i = start; i < end; ++i) {
        int b = batch[i];
        if (b != cg) {
            atomAddF(&sums[cg * 64 + f], acc);
            if (f == 0) atomAddF(&cnt[cg], (float)count);
            acc = 0.f; count = 0; cg = b;
        }
        acc += h[(size_t)i * 64 + f];
        ++count;
    }
    atomAddF(&sums[cg * 64 + f], acc);
    if (f == 0) atomAddF(&cnt[cg], (float)count);
}

// ---------- final: out = (sums/max(cnt,1)) @ lin2_w + lin2_b ----------
__global__ __launch_bounds__(64) void k_final(const float* __restrict__ sums,
                                              const float* __restrict__ cnt,
                                              const float* __restrict__ w,
                                              const float* __restrict__ b,
                                              float* __restrict__ out) {
    int g = blockIdx.x, f = threadIdx.x;
    float c = fmaxf(cnt[g], 1.0f);
    float p = sums[g * 64 + f] / c;
#pragma unroll
    for (int cls = 0; cls < NCLS; ++cls) {
        float v = p * w[f * 10 + cls];
#pragma unroll
        for (int o = 32; o > 0; o >>= 1) v += __shfl_down(v, o);
        if (f == 0) out[g * 10 + cls] = v + b[cls];
    }
}

extern "C" void kernel_launch(void* const* d_in, const int* in_sizes, int n_in,
                              void* d_out, int out_size, void* d_ws, size_t ws_size,
                              hipStream_t stream) {
    const float* x       = (const float*)d_in[0];
    const int*   ei      = (const int*)d_in[1];
    const int*   batch   = (const int*)d_in[2];
    const float* drop_u  = (const float*)d_in[4];
    const float* lin1_w  = (const float*)d_in[5];
    const float* lin1_b  = (const float*)d_in[6];
    const float* conv1_w = (const float*)d_in[7];
    const float* conv1_b = (const float*)d_in[8];
    const float* conv2_w = (const float*)d_in[9];
    const float* conv2_b = (const float*)d_in[10];
    const float* lin2_w  = (const float*)d_in[11];
    const float* lin2_b  = (const float*)d_in[12];
    float* out = (float*)d_out;

    const int N = in_sizes[0] / DIN;        // 100000
    const int E = in_sizes[1] / 2;          // 1600000
    const int* src = ei;
    const int* dst = ei + E;

    // workspace layout
    float* ws    = (float*)d_ws;
    float* h1    = ws;                              // N*128  (reused as h2: N*64)
    float* out1  = ws + (size_t)N * 128;            // N*128  (reused as out2: N*64)
    float* dis   = ws + (size_t)2 * N * 128;        // N
    float* W12   = dis + N;                         // 16384
    float* c1pb  = W12 + 16384;                     // 128
    float* sums  = c1pb + 128;                      // 128*64
    float* cntp  = sums + NGRAPH * 64;              // 128
    int*   cnt   = (int*)(cntp + NGRAPH);           // N
    int*   row_start = cnt + N;                     // N+1
    int*   cursor    = row_start + N + 1;           // N
    int*   part      = cursor + N;                  // 256 (scan partials)
    int*   col       = part + 256;                  // E
    float* h2    = h1;
    float* out2  = out1;

    // fused weight + pre-aggregation bias
    k_w12<<<129, 128, 0, stream>>>(lin1_w, lin1_b, conv1_w, W12, c1pb);

    // CSR build: histogram -> dis -> 3-phase scan -> fill
    k_zeroi<<<(N + 255) / 256, 256, 0, stream>>>(cnt, N);
    k_count<<<(E + 255) / 256, 256, 0, stream>>>(dst, cnt, E);
    k_dis<<<(N + 255) / 256, 256, 0, stream>>>(cnt, dis, N);
    const int scanB = (N + SCAN_CHUNK - 1) / SCAN_CHUNK;   // 98 <= 256
    k_scan_part<<<scanB, 256, 0, stream>>>(cnt, part, N);
    k_scan_mid<<<1, 256, 0, stream>>>(part, row_start, scanB, N);
    k_scan_fin<<<scanB, 256, 0, stream>>>(cnt, part, row_start, cursor, N);
    k_fill<<<(E + 255) / 256, 256, 0, stream>>>(src, dst, cursor, col, E);

    // h1 = x @ W12 + c1pb
    const int gemmGrid = (N + 63) / 64;
    k_gemm<128, false><<<gemmGrid, 256, 0, stream>>>(x, W12, c1pb, nullptr, h1, N);

    // conv1 aggregation (gather, bias+self-loop folded)
    k_gather<128><<<((size_t)N * 32 + 255) / 256, 256, 0, stream>>>(h1, row_start, col, dis, conv1_b, out1, N);

    // h2 = relu(dropout(out1)) @ conv2_w
    k_gemm<64, true><<<gemmGrid, 256, 0, stream>>>(out1, conv2_w, nullptr, drop_u, h2, N);

    // conv2 aggregation
    k_gather<64><<<((size_t)N * 16 + 255) / 256, 256, 0, stream>>>(h2, row_start, col, dis, conv2_b, out2, N);

    // pooled mean + classifier
    k_zero<<<(NGRAPH * 64 + NGRAPH + 255) / 256, 256, 0, stream>>>(sums, NGRAPH * 64 + NGRAPH);
    k_pool<<<128, 256, 0, stream>>>(out2, batch, sums, cntp, N);
    k_final<<<NGRAPH, 64, 0, stream>>>(sums, cntp, lin2_w, lin2_b, out);
}

// Round 4
// 626.729 us; speedup vs baseline: 7.1132x; 1.1441x over previous
//
#include <hip/hip_runtime.h>
#include <hip/hip_bf16.h>

// Problem constants (fixed by the reference file)
#define DIN   128
#define HID2  64
#define NCLS  10
#define NGRAPH 128
#define SCAN_CHUNK 1024

__device__ __forceinline__ void atomAddF(float* p, float v) {
    unsafeAtomicAdd(p, v);
}

// float -> bf16 (round-to-nearest-even), finite inputs
__device__ __forceinline__ unsigned short f2bf(float f) {
    unsigned int u = __float_as_uint(f);
    u += 0x7fffu + ((u >> 16) & 1u);
    return (unsigned short)(u >> 16);
}

// ---------- K0: W12 = lin1_w @ conv1_w ; c1preb = lin1_b @ conv1_w ----------
__global__ __launch_bounds__(128) void k_w12(const float* __restrict__ lw,
                                             const float* __restrict__ lb,
                                             const float* __restrict__ cw,
                                             float* __restrict__ W12,
                                             float* __restrict__ c1preb) {
    int i = blockIdx.x, j = threadIdx.x;
    const float* arow = (i < 128) ? (lw + i * 128) : lb;
    float acc = 0.f;
#pragma unroll 8
    for (int k = 0; k < 128; ++k) acc += arow[k] * cw[k * 128 + j];
    if (i < 128) W12[i * 128 + j] = acc;
    else         c1preb[j] = acc;
}

// ---------- CSR build ----------
__global__ __launch_bounds__(256) void k_zeroi(int* p, int n) {
    int i = blockIdx.x * 256 + threadIdx.x;
    if (i < n) p[i] = 0;
}
__global__ __launch_bounds__(256) void k_zero(float* p, int n) {
    int i = blockIdx.x * 256 + threadIdx.x;
    if (i < n) p[i] = 0.0f;
}
__global__ __launch_bounds__(256) void k_count(const int* __restrict__ dst, int* cnt, int E) {
    int e = blockIdx.x * 256 + threadIdx.x;
    if (e < E) atomicAdd(&cnt[dst[e]], 1);
}
__global__ __launch_bounds__(256) void k_dis(const int* __restrict__ cnt, float* dis, int n) {
    int i = blockIdx.x * 256 + threadIdx.x;
    if (i < n) dis[i] = rsqrtf((float)(cnt[i] + 1));
}

// --- 3-phase parallel exclusive scan ---
__global__ __launch_bounds__(256) void k_scan_part(const int* __restrict__ cnt,
                                                   int* __restrict__ part, int n) {
    int base = blockIdx.x * SCAN_CHUNK + threadIdx.x * 4;
    int s = 0;
#pragma unroll
    for (int j = 0; j < 4; ++j) { int i = base + j; if (i < n) s += cnt[i]; }
#pragma unroll
    for (int o = 32; o > 0; o >>= 1) s += __shfl_down(s, o);
    __shared__ int wsum[4];
    if ((threadIdx.x & 63) == 0) wsum[threadIdx.x >> 6] = s;
    __syncthreads();
    if (threadIdx.x == 0) part[blockIdx.x] = wsum[0] + wsum[1] + wsum[2] + wsum[3];
}
__global__ __launch_bounds__(256) void k_scan_mid(int* __restrict__ part,
                                                  int* __restrict__ row_start,
                                                  int B, int n) {
    __shared__ int sh[256];
    int t = threadIdx.x;
    int v = (t < B) ? part[t] : 0;
    sh[t] = v;
    __syncthreads();
    for (int off = 1; off < 256; off <<= 1) {
        int u = (t >= off) ? sh[t - off] : 0;
        __syncthreads();
        sh[t] += u;
        __syncthreads();
    }
    if (t < B) part[t] = sh[t] - v;
    if (t == 255) row_start[n] = sh[255];
}
__global__ __launch_bounds__(256) void k_scan_fin(const int* __restrict__ cnt,
                                                  const int* __restrict__ part,
                                                  int* __restrict__ row_start,
                                                  int* __restrict__ cursor, int n) {
    __shared__ int sh[256];
    int t = threadIdx.x;
    int base = blockIdx.x * SCAN_CHUNK + t * 4;
    int c[4]; int s = 0;
#pragma unroll
    for (int j = 0; j < 4; ++j) { int i = base + j; c[j] = (i < n) ? cnt[i] : 0; s += c[j]; }
    sh[t] = s;
    __syncthreads();
    for (int off = 1; off < 256; off <<= 1) {
        int u = (t >= off) ? sh[t - off] : 0;
        __syncthreads();
        sh[t] += u;
        __syncthreads();
    }
    int excl = part[blockIdx.x] + sh[t] - s;
#pragma unroll
    for (int j = 0; j < 4; ++j) {
        int i = base + j;
        if (i < n) { row_start[i] = excl; cursor[i] = excl; }
        excl += c[j];
    }
}

__global__ __launch_bounds__(256) void k_fill(const int* __restrict__ src,
                                              const int* __restrict__ dst,
                                              int* __restrict__ cursor,
                                              int* __restrict__ col, int E) {
    int e = blockIdx.x * 256 + threadIdx.x;
    if (e >= E) return;
    int pos = atomicAdd(&cursor[dst[e]], 1);
    col[pos] = src[e];
}

// ---------- tiled fp32 GEMM, bf16 output: out[M x NCOL] = f(A) @ W (+bias) ----------
template <int NCOL, bool MASK>
__global__ __launch_bounds__(256) void k_gemm(const float* __restrict__ A,
                                              const float* __restrict__ W,
                                              const float* __restrict__ bias,
                                              const float* __restrict__ du,
                                              unsigned short* __restrict__ out, int M) {
    constexpr int CG = NCOL / 4;
    constexpr int RSTRIDE = 256 / CG;
    constexpr int RPT = 64 / RSTRIDE;
    __shared__ float As[64][33];

    const int tid = threadIdx.x;
    const int cg = tid % CG;
    const int ry = tid / CG;
    const int row0 = blockIdx.x * 64;

    float4 acc[RPT];
#pragma unroll
    for (int j = 0; j < RPT; ++j) acc[j] = make_float4(0.f, 0.f, 0.f, 0.f);

    for (int kk = 0; kk < 128; kk += 32) {
        __syncthreads();
#pragma unroll
        for (int t = tid; t < 512; t += 256) {
            int r = t >> 3;
            int c4 = t & 7;
            int gr = row0 + r;
            float4 v = make_float4(0.f, 0.f, 0.f, 0.f);
            if (gr < M) {
                v = *(const float4*)(A + (size_t)gr * 128 + kk + c4 * 4);
                if (MASK) {
                    float4 u = *(const float4*)(du + (size_t)gr * 128 + kk + c4 * 4);
                    v.x = (u.x >= 0.5f) ? 2.f * fmaxf(v.x, 0.f) : 0.f;
                    v.y = (u.y >= 0.5f) ? 2.f * fmaxf(v.y, 0.f) : 0.f;
                    v.z = (u.z >= 0.5f) ? 2.f * fmaxf(v.z, 0.f) : 0.f;
                    v.w = (u.w >= 0.5f) ? 2.f * fmaxf(v.w, 0.f) : 0.f;
                }
            }
            As[r][c4 * 4 + 0] = v.x;
            As[r][c4 * 4 + 1] = v.y;
            As[r][c4 * 4 + 2] = v.z;
            As[r][c4 * 4 + 3] = v.w;
        }
        __syncthreads();
#pragma unroll 4
        for (int k = 0; k < 32; ++k) {
            const float4 wv = *(const float4*)(W + (size_t)(kk + k) * NCOL + cg * 4);
            float a[RPT];
#pragma unroll
            for (int j = 0; j < RPT; ++j) a[j] = As[ry + RSTRIDE * j][k];
#pragma unroll
            for (int j = 0; j < RPT; ++j) {
                acc[j].x = fmaf(a[j], wv.x, acc[j].x);
                acc[j].y = fmaf(a[j], wv.y, acc[j].y);
                acc[j].z = fmaf(a[j], wv.z, acc[j].z);
                acc[j].w = fmaf(a[j], wv.w, acc[j].w);
            }
        }
    }
    float4 b4 = make_float4(0.f, 0.f, 0.f, 0.f);
    if (bias) b4 = *(const float4*)(bias + cg * 4);
#pragma unroll
    for (int j = 0; j < RPT; ++j) {
        int gr = row0 + ry + RSTRIDE * j;
        if (gr < M) {
            ushort4 r;
            r.x = f2bf(acc[j].x + b4.x);
            r.y = f2bf(acc[j].y + b4.y);
            r.z = f2bf(acc[j].z + b4.z);
            r.w = f2bf(acc[j].w + b4.w);
            *(ushort4*)(out + (size_t)gr * NCOL + cg * 4) = r;
        }
    }
}

// ---------- CSR gather (bf16 input rows, fp32 accumulate+output) ----------
// out[d] = bias + dis_d*(dis_d*h[d] + sum_{s in row(d)} dis_s*h[s])
__device__ __forceinline__ void bfacc(uint4 v, float d, float* acc) {
    acc[0] = fmaf(d, __uint_as_float(v.x << 16),        acc[0]);
    acc[1] = fmaf(d, __uint_as_float(v.x & 0xffff0000u), acc[1]);
    acc[2] = fmaf(d, __uint_as_float(v.y << 16),        acc[2]);
    acc[3] = fmaf(d, __uint_as_float(v.y & 0xffff0000u), acc[3]);
    acc[4] = fmaf(d, __uint_as_float(v.z << 16),        acc[4]);
    acc[5] = fmaf(d, __uint_as_float(v.z & 0xffff0000u), acc[5]);
    acc[6] = fmaf(d, __uint_as_float(v.w << 16),        acc[6]);
    acc[7] = fmaf(d, __uint_as_float(v.w & 0xffff0000u), acc[7]);
}

template <int NCOL>
__global__ __launch_bounds__(256) void k_gather(const unsigned short* __restrict__ h,
                                                const int* __restrict__ row_start,
                                                const int* __restrict__ col,
                                                const float* __restrict__ dis,
                                                const float* __restrict__ bias,
                                                float* __restrict__ out, int n) {
    constexpr int LPN = NCOL / 8;       // lanes per node, 8 bf16 (16B) per lane
    const int node = (blockIdx.x * 256 + threadIdx.x) / LPN;
    const int l = threadIdx.x % LPN;
    if (node >= n) return;
    const int coff = l * 8;             // bf16 element offset within row

    const float dn = dis[node];
    float acc[8];
    {
        uint4 v = *(const uint4*)(h + (size_t)node * NCOL + coff);
#pragma unroll
        for (int q = 0; q < 8; ++q) acc[q] = 0.f;
        bfacc(v, dn, acc);
    }

    const int beg = row_start[node], end = row_start[node + 1];
    int j = beg;
    for (; j + 1 < end; j += 2) {
        const int s0 = col[j], s1 = col[j + 1];
        const float d0 = dis[s0], d1 = dis[s1];
        const uint4 v0 = *(const uint4*)(h + (size_t)s0 * NCOL + coff);
        const uint4 v1 = *(const uint4*)(h + (size_t)s1 * NCOL + coff);
        bfacc(v0, d0, acc);
        bfacc(v1, d1, acc);
    }
    if (j < end) {
        const int s0 = col[j];
        const float d0 = dis[s0];
        const uint4 v0 = *(const uint4*)(h + (size_t)s0 * NCOL + coff);
        bfacc(v0, d0, acc);
    }

    float4 r0, r1;
    const float4 b0 = *(const float4*)(bias + coff);
    const float4 b1 = *(const float4*)(bias + coff + 4);
    r0.x = fmaf(dn, acc[0], b0.x); r0.y = fmaf(dn, acc[1], b0.y);
    r0.z = fmaf(dn, acc[2], b0.z); r0.w = fmaf(dn, acc[3], b0.w);
    r1.x = fmaf(dn, acc[4], b1.x); r1.y = fmaf(dn, acc[5], b1.y);
    r1.z = fmaf(dn, acc[6], b1.z); r1.w = fmaf(dn, acc[7], b1.w);
    float* o = out + (size_t)node * NCOL + coff;
    *(float4*)(o) = r0;
    *(float4*)(o + 4) = r1;
}

// ---------- pooling ----------
__global__ __launch_bounds__(256) void k_pool(const float* __restrict__ h,
                                              const int* __restrict__ batch,
                                              float* __restrict__ sums,
                                              float* __restrict__ cnt,
                                              int n) {
    int gid = (blockIdx.x * 256 + threadIdx.x) / 64;
    int f = threadIdx.x % 64;
    int ngroups = gridDim.x * 4;
    int per = (n + ngroups - 1) / ngroups;
    int start = gid * per;
    int end = min(n, start + per);
    if (start >= end) return;
    int cg = batch[start];
    float acc = 0.f;
    int count = 0;
    for (int i = start; i < end; ++i) {
        int b = batch[i];
        if (b != cg) {
            atomAddF(&sums[cg * 64 + f], acc);
            if (f == 0) atomAddF(&cnt[cg], (float)count);
            acc = 0.f; count = 0; cg = b;
        }
        acc += h[(size_t)i * 64 + f];
        ++count;
    }
    atomAddF(&sums[cg * 64 + f], acc);
    if (f == 0) atomAddF(&cnt[cg], (float)count);
}

// ---------- final ----------
__global__ __launch_bounds__(64) void k_final(const float* __restrict__ sums,
                                              const float* __restrict__ cnt,
                                              const float* __restrict__ w,
                                              const float* __restrict__ b,
                                              float* __restrict__ out) {
    int g = blockIdx.x, f = threadIdx.x;
    float c = fmaxf(cnt[g], 1.0f);
    float p = sums[g * 64 + f] / c;
#pragma unroll
    for (int cls = 0; cls < NCLS; ++cls) {
        float v = p * w[f * 10 + cls];
#pragma unroll
        for (int o = 32; o > 0; o >>= 1) v += __shfl_down(v, o);
        if (f == 0) out[g * 10 + cls] = v + b[cls];
    }
}

extern "C" void kernel_launch(void* const* d_in, const int* in_sizes, int n_in,
                              void* d_out, int out_size, void* d_ws, size_t ws_size,
                              hipStream_t stream) {
    const float* x       = (const float*)d_in[0];
    const int*   ei      = (const int*)d_in[1];
    const int*   batch   = (const int*)d_in[2];
    const float* drop_u  = (const float*)d_in[4];
    const float* lin1_w  = (const float*)d_in[5];
    const float* lin1_b  = (const float*)d_in[6];
    const float* conv1_w = (const float*)d_in[7];
    const float* conv1_b = (const float*)d_in[8];
    const float* conv2_w = (const float*)d_in[9];
    const float* conv2_b = (const float*)d_in[10];
    const float* lin2_w  = (const float*)d_in[11];
    const float* lin2_b  = (const float*)d_in[12];
    float* out = (float*)d_out;

    const int N = in_sizes[0] / DIN;        // 100000
    const int E = in_sizes[1] / 2;          // 1600000
    const int* src = ei;
    const int* dst = ei + E;

    // workspace layout (float units)
    float* ws    = (float*)d_ws;
    float* out1  = ws;                                  // N*128 fp32 (reused as out2: N*64)
    unsigned short* h1b = (unsigned short*)(ws + (size_t)N * 128);  // N*128 bf16 (reused as h2b: N*64)
    float* dis   = ws + (size_t)N * 128 + (size_t)N * 64;           // N
    float* W12   = dis + N;                             // 16384
    float* c1pb  = W12 + 16384;                         // 128
    float* sums  = c1pb + 128;                          // 128*64
    float* cntp  = sums + NGRAPH * 64;                  // 128
    int*   cnt   = (int*)(cntp + NGRAPH);               // N
    int*   row_start = cnt + N;                         // N+1
    int*   cursor    = row_start + N + 1;               // N
    int*   part      = cursor + N;                      // 256
    int*   col       = part + 256;                      // E
    unsigned short* h2b = h1b;
    float* out2  = out1;

    // fused weight + pre-aggregation bias
    k_w12<<<129, 128, 0, stream>>>(lin1_w, lin1_b, conv1_w, W12, c1pb);

    // CSR build
    k_zeroi<<<(N + 255) / 256, 256, 0, stream>>>(cnt, N);
    k_count<<<(E + 255) / 256, 256, 0, stream>>>(dst, cnt, E);
    k_dis<<<(N + 255) / 256, 256, 0, stream>>>(cnt, dis, N);
    const int scanB = (N + SCAN_CHUNK - 1) / SCAN_CHUNK;
    k_scan_part<<<scanB, 256, 0, stream>>>(cnt, part, N);
    k_scan_mid<<<1, 256, 0, stream>>>(part, row_start, scanB, N);
    k_scan_fin<<<scanB, 256, 0, stream>>>(cnt, part, row_start, cursor, N);
    k_fill<<<(E + 255) / 256, 256, 0, stream>>>(src, dst, cursor, col, E);

    // h1b = bf16(x @ W12 + c1pb)
    const int gemmGrid = (N + 63) / 64;
    k_gemm<128, false><<<gemmGrid, 256, 0, stream>>>(x, W12, c1pb, nullptr, h1b, N);

    // conv1 aggregation: out1 = fp32 gather of bf16 h1b
    k_gather<128><<<((size_t)N * 16 + 255) / 256, 256, 0, stream>>>(h1b, row_start, col, dis, conv1_b, out1, N);

    // h2b = bf16(relu(dropout(out1)) @ conv2_w)
    k_gemm<64, true><<<gemmGrid, 256, 0, stream>>>(out1, conv2_w, nullptr, drop_u, h2b, N);

    // conv2 aggregation: out2 = fp32 gather of bf16 h2b
    k_gather<64><<<((size_t)N * 8 + 255) / 256, 256, 0, stream>>>(h2b, row_start, col, dis, conv2_b, out2, N);

    // pooled mean + classifier
    k_zero<<<(NGRAPH * 64 + NGRAPH + 255) / 256, 256, 0, stream>>>(sums, NGRAPH * 64 + NGRAPH);
    k_pool<<<128, 256, 0, stream>>>(out2, batch, sums, cntp, N);
    k_final<<<NGRAPH, 64, 0, stream>>>(sums, cntp, lin2_w, lin2_b, out);
}

// Round 5
// 602.431 us; speedup vs baseline: 7.4001x; 1.0403x over previous
//
#include <hip/hip_runtime.h>
#include <hip/hip_bf16.h>

// Problem constants (fixed by the reference file)
#define DIN   128
#define HID2  64
#define NCLS  10
#define NGRAPH 128
#define SCAN_CHUNK 1024

__device__ __forceinline__ void atomAddF(float* p, float v) {
    unsafeAtomicAdd(p, v);
}

// float -> bf16 (round-to-nearest-even), finite inputs
__device__ __forceinline__ unsigned short f2bf(float f) {
    unsigned int u = __float_as_uint(f);
    u += 0x7fffu + ((u >> 16) & 1u);
    return (unsigned short)(u >> 16);
}

// ---------- K0: W12 = lin1_w @ conv1_w ; c1preb = lin1_b @ conv1_w ----------
__global__ __launch_bounds__(128) void k_w12(const float* __restrict__ lw,
                                             const float* __restrict__ lb,
                                             const float* __restrict__ cw,
                                             float* __restrict__ W12,
                                             float* __restrict__ c1preb) {
    int i = blockIdx.x, j = threadIdx.x;
    const float* arow = (i < 128) ? (lw + i * 128) : lb;
    float acc = 0.f;
#pragma unroll 8
    for (int k = 0; k < 128; ++k) acc += arow[k] * cw[k * 128 + j];
    if (i < 128) W12[i * 128 + j] = acc;
    else         c1preb[j] = acc;
}

// ---------- CSR build (XCD-localized) ----------
__global__ __launch_bounds__(256) void k_zeroi(int* p, int n) {
    int i = blockIdx.x * 256 + threadIdx.x;
    if (i < n) p[i] = 0;
}
__global__ __launch_bounds__(256) void k_zero(float* p, int n) {
    int i = blockIdx.x * 256 + threadIdx.x;
    if (i < n) p[i] = 0.0f;
}

// Partitioned histogram: group g (= blockIdx&7, heuristically pinned to XCD g)
// scans all edges, counts only dst in its node range -> cnt slice stays in its L2.
__global__ __launch_bounds__(256) void k_count(const int* __restrict__ dst,
                                               int* __restrict__ cnt, int E, int N) {
    const int grp = blockIdx.x & 7;
    const int chunk = (N + 7) / 8;
    const int lo = grp * chunk, hi = min(N, lo + chunk);
    const int nb = gridDim.x >> 3;
    const int bi = blockIdx.x >> 3;
    for (int e = bi * 256 + threadIdx.x; e < E; e += nb * 256) {
        int d = dst[e];
        if (d >= lo && d < hi) atomicAdd(&cnt[d], 1);
    }
}
__global__ __launch_bounds__(256) void k_dis(const int* __restrict__ cnt, float* dis, int n) {
    int i = blockIdx.x * 256 + threadIdx.x;
    if (i < n) dis[i] = rsqrtf((float)(cnt[i] + 1));
}

// --- 3-phase parallel exclusive scan ---
__global__ __launch_bounds__(256) void k_scan_part(const int* __restrict__ cnt,
                                                   int* __restrict__ part, int n) {
    int base = blockIdx.x * SCAN_CHUNK + threadIdx.x * 4;
    int s = 0;
#pragma unroll
    for (int j = 0; j < 4; ++j) { int i = base + j; if (i < n) s += cnt[i]; }
#pragma unroll
    for (int o = 32; o > 0; o >>= 1) s += __shfl_down(s, o);
    __shared__ int wsum[4];
    if ((threadIdx.x & 63) == 0) wsum[threadIdx.x >> 6] = s;
    __syncthreads();
    if (threadIdx.x == 0) part[blockIdx.x] = wsum[0] + wsum[1] + wsum[2] + wsum[3];
}
__global__ __launch_bounds__(256) void k_scan_mid(int* __restrict__ part,
                                                  int* __restrict__ row_start,
                                                  int B, int n) {
    __shared__ int sh[256];
    int t = threadIdx.x;
    int v = (t < B) ? part[t] : 0;
    sh[t] = v;
    __syncthreads();
    for (int off = 1; off < 256; off <<= 1) {
        int u = (t >= off) ? sh[t - off] : 0;
        __syncthreads();
        sh[t] += u;
        __syncthreads();
    }
    if (t < B) part[t] = sh[t] - v;
    if (t == 255) row_start[n] = sh[255];
}
__global__ __launch_bounds__(256) void k_scan_fin(const int* __restrict__ cnt,
                                                  const int* __restrict__ part,
                                                  int* __restrict__ row_start,
                                                  int* __restrict__ cursor, int n) {
    __shared__ int sh[256];
    int t = threadIdx.x;
    int base = blockIdx.x * SCAN_CHUNK + t * 4;
    int c[4]; int s = 0;
#pragma unroll
    for (int j = 0; j < 4; ++j) { int i = base + j; c[j] = (i < n) ? cnt[i] : 0; s += c[j]; }
    sh[t] = s;
    __syncthreads();
    for (int off = 1; off < 256; off <<= 1) {
        int u = (t >= off) ? sh[t - off] : 0;
        __syncthreads();
        sh[t] += u;
        __syncthreads();
    }
    int excl = part[blockIdx.x] + sh[t] - s;
#pragma unroll
    for (int j = 0; j < 4; ++j) {
        int i = base + j;
        if (i < n) { row_start[i] = excl; cursor[i] = excl; }
        excl += c[j];
    }
}

// Partitioned fill: group g handles only dst in its node range, so its col/cursor
// slices (~0.8 MB / 50 KB) live in one XCD's L2 -> full-line writebacks, local atomics.
__global__ __launch_bounds__(256) void k_fill(const int* __restrict__ src,
                                              const int* __restrict__ dst,
                                              int* __restrict__ cursor,
                                              int* __restrict__ col, int E, int N) {
    const int grp = blockIdx.x & 7;
    const int chunk = (N + 7) / 8;
    const int lo = grp * chunk, hi = min(N, lo + chunk);
    const int nb = gridDim.x >> 3;
    const int bi = blockIdx.x >> 3;
    for (int e = bi * 256 + threadIdx.x; e < E; e += nb * 256) {
        int d = dst[e];
        if (d >= lo && d < hi) {
            int pos = atomicAdd(&cursor[d], 1);
            col[pos] = src[e];
        }
    }
}

// ---------- tiled fp32 GEMM, bf16 output: out[M x NCOL] = f(A) @ W (+bias) ----------
template <int NCOL, bool MASK>
__global__ __launch_bounds__(256) void k_gemm(const float* __restrict__ A,
                                              const float* __restrict__ W,
                                              const float* __restrict__ bias,
                                              const float* __restrict__ du,
                                              unsigned short* __restrict__ out, int M) {
    constexpr int CG = NCOL / 4;
    constexpr int RSTRIDE = 256 / CG;
    constexpr int RPT = 64 / RSTRIDE;
    __shared__ float As[64][33];

    const int tid = threadIdx.x;
    const int cg = tid % CG;
    const int ry = tid / CG;
    const int row0 = blockIdx.x * 64;

    float4 acc[RPT];
#pragma unroll
    for (int j = 0; j < RPT; ++j) acc[j] = make_float4(0.f, 0.f, 0.f, 0.f);

    for (int kk = 0; kk < 128; kk += 32) {
        __syncthreads();
#pragma unroll
        for (int t = tid; t < 512; t += 256) {
            int r = t >> 3;
            int c4 = t & 7;
            int gr = row0 + r;
            float4 v = make_float4(0.f, 0.f, 0.f, 0.f);
            if (gr < M) {
                v = *(const float4*)(A + (size_t)gr * 128 + kk + c4 * 4);
                if (MASK) {
                    float4 u = *(const float4*)(du + (size_t)gr * 128 + kk + c4 * 4);
                    v.x = (u.x >= 0.5f) ? 2.f * fmaxf(v.x, 0.f) : 0.f;
                    v.y = (u.y >= 0.5f) ? 2.f * fmaxf(v.y, 0.f) : 0.f;
                    v.z = (u.z >= 0.5f) ? 2.f * fmaxf(v.z, 0.f) : 0.f;
                    v.w = (u.w >= 0.5f) ? 2.f * fmaxf(v.w, 0.f) : 0.f;
                }
            }
            As[r][c4 * 4 + 0] = v.x;
            As[r][c4 * 4 + 1] = v.y;
            As[r][c4 * 4 + 2] = v.z;
            As[r][c4 * 4 + 3] = v.w;
        }
        __syncthreads();
#pragma unroll 4
        for (int k = 0; k < 32; ++k) {
            const float4 wv = *(const float4*)(W + (size_t)(kk + k) * NCOL + cg * 4);
            float a[RPT];
#pragma unroll
            for (int j = 0; j < RPT; ++j) a[j] = As[ry + RSTRIDE * j][k];
#pragma unroll
            for (int j = 0; j < RPT; ++j) {
                acc[j].x = fmaf(a[j], wv.x, acc[j].x);
                acc[j].y = fmaf(a[j], wv.y, acc[j].y);
                acc[j].z = fmaf(a[j], wv.z, acc[j].z);
                acc[j].w = fmaf(a[j], wv.w, acc[j].w);
            }
        }
    }
    float4 b4 = make_float4(0.f, 0.f, 0.f, 0.f);
    if (bias) b4 = *(const float4*)(bias + cg * 4);
#pragma unroll
    for (int j = 0; j < RPT; ++j) {
        int gr = row0 + ry + RSTRIDE * j;
        if (gr < M) {
            ushort4 r;
            r.x = f2bf(acc[j].x + b4.x);
            r.y = f2bf(acc[j].y + b4.y);
            r.z = f2bf(acc[j].z + b4.z);
            r.w = f2bf(acc[j].w + b4.w);
            *(ushort4*)(out + (size_t)gr * NCOL + cg * 4) = r;
        }
    }
}

// ---------- CSR gather (bf16 input rows, fp32 accumulate+output) ----------
__device__ __forceinline__ void bfacc(uint4 v, float d, float* acc) {
    acc[0] = fmaf(d, __uint_as_float(v.x << 16),        acc[0]);
    acc[1] = fmaf(d, __uint_as_float(v.x & 0xffff0000u), acc[1]);
    acc[2] = fmaf(d, __uint_as_float(v.y << 16),        acc[2]);
    acc[3] = fmaf(d, __uint_as_float(v.y & 0xffff0000u), acc[3]);
    acc[4] = fmaf(d, __uint_as_float(v.z << 16),        acc[4]);
    acc[5] = fmaf(d, __uint_as_float(v.z & 0xffff0000u), acc[5]);
    acc[6] = fmaf(d, __uint_as_float(v.w << 16),        acc[6]);
    acc[7] = fmaf(d, __uint_as_float(v.w & 0xffff0000u), acc[7]);
}

template <int NCOL>
__global__ __launch_bounds__(256) void k_gather(const unsigned short* __restrict__ h,
                                                const int* __restrict__ row_start,
                                                const int* __restrict__ col,
                                                const float* __restrict__ dis,
                                                const float* __restrict__ bias,
                                                float* __restrict__ out, int n) {
    constexpr int LPN = NCOL / 8;
    const int node = (blockIdx.x * 256 + threadIdx.x) / LPN;
    const int l = threadIdx.x % LPN;
    if (node >= n) return;
    const int coff = l * 8;

    const float dn = dis[node];
    float acc[8];
    {
        uint4 v = *(const uint4*)(h + (size_t)node * NCOL + coff);
#pragma unroll
        for (int q = 0; q < 8; ++q) acc[q] = 0.f;
        bfacc(v, dn, acc);
    }

    const int beg = row_start[node], end = row_start[node + 1];
    int j = beg;
    for (; j + 1 < end; j += 2) {
        const int s0 = col[j], s1 = col[j + 1];
        const float d0 = dis[s0], d1 = dis[s1];
        const uint4 v0 = *(const uint4*)(h + (size_t)s0 * NCOL + coff);
        const uint4 v1 = *(const uint4*)(h + (size_t)s1 * NCOL + coff);
        bfacc(v0, d0, acc);
        bfacc(v1, d1, acc);
    }
    if (j < end) {
        const int s0 = col[j];
        const float d0 = dis[s0];
        const uint4 v0 = *(const uint4*)(h + (size_t)s0 * NCOL + coff);
        bfacc(v0, d0, acc);
    }

    float4 r0, r1;
    const float4 b0 = *(const float4*)(bias + coff);
    const float4 b1 = *(const float4*)(bias + coff + 4);
    r0.x = fmaf(dn, acc[0], b0.x); r0.y = fmaf(dn, acc[1], b0.y);
    r0.z = fmaf(dn, acc[2], b0.z); r0.w = fmaf(dn, acc[3], b0.w);
    r1.x = fmaf(dn, acc[4], b1.x); r1.y = fmaf(dn, acc[5], b1.y);
    r1.z = fmaf(dn, acc[6], b1.z); r1.w = fmaf(dn, acc[7], b1.w);
    float* o = out + (size_t)node * NCOL + coff;
    *(float4*)(o) = r0;
    *(float4*)(o + 4) = r1;
}

// ---------- pooling ----------
__global__ __launch_bounds__(256) void k_pool(const float* __restrict__ h,
                                              const int* __restrict__ batch,
                                              float* __restrict__ sums,
                                              float* __restrict__ cnt,
                                              int n) {
    int gid = (blockIdx.x * 256 + threadIdx.x) / 64;
    int f = threadIdx.x % 64;
    int ngroups = gridDim.x * 4;
    int per = (n + ngroups - 1) / ngroups;
    int start = gid * per;
    int end = min(n, start + per);
    if (start >= end) return;
    int cg = batch[start];
    float acc = 0.f;
    int count = 0;
    for (int i = start; i < end; ++i) {
        int b = batch[i];
        if (b != cg) {
            atomAddF(&sums[cg * 64 + f], acc);
            if (f == 0) atomAddF(&cnt[cg], (float)count);
            acc = 0.f; count = 0; cg = b;
        }
        acc += h[(size_t)i * 64 + f];
        ++count;
    }
    atomAddF(&sums[cg * 64 + f], acc);
    if (f == 0) atomAddF(&cnt[cg], (float)count);
}

// ---------- final ----------
__global__ __launch_bounds__(64) void k_final(const float* __restrict__ sums,
                                              const float* __restrict__ cnt,
                                              const float* __restrict__ w,
                                              const float* __restrict__ b,
                                              float* __restrict__ out) {
    int g = blockIdx.x, f = threadIdx.x;
    float c = fmaxf(cnt[g], 1.0f);
    float p = sums[g * 64 + f] / c;
#pragma unroll
    for (int cls = 0; cls < NCLS; ++cls) {
        float v = p * w[f * 10 + cls];
#pragma unroll
        for (int o = 32; o > 0; o >>= 1) v += __shfl_down(v, o);
        if (f == 0) out[g * 10 + cls] = v + b[cls];
    }
}

extern "C" void kernel_launch(void* const* d_in, const int* in_sizes, int n_in,
                              void* d_out, int out_size, void* d_ws, size_t ws_size,
                              hipStream_t stream) {
    const float* x       = (const float*)d_in[0];
    const int*   ei      = (const int*)d_in[1];
    const int*   batch   = (const int*)d_in[2];
    const float* drop_u  = (const float*)d_in[4];
    const float* lin1_w  = (const float*)d_in[5];
    const float* lin1_b  = (const float*)d_in[6];
    const float* conv1_w = (const float*)d_in[7];
    const float* conv1_b = (const float*)d_in[8];
    const float* conv2_w = (const float*)d_in[9];
    const float* conv2_b = (const float*)d_in[10];
    const float* lin2_w  = (const float*)d_in[11];
    const float* lin2_b  = (const float*)d_in[12];
    float* out = (float*)d_out;

    const int N = in_sizes[0] / DIN;        // 100000
    const int E = in_sizes[1] / 2;          // 1600000
    const int* src = ei;
    const int* dst = ei + E;

    // workspace layout (float units)
    float* ws    = (float*)d_ws;
    float* out1  = ws;                                  // N*128 fp32 (reused as out2: N*64)
    unsigned short* h1b = (unsigned short*)(ws + (size_t)N * 128);  // N*128 bf16 (reused as h2b: N*64)
    float* dis   = ws + (size_t)N * 128 + (size_t)N * 64;           // N
    float* W12   = dis + N;                             // 16384
    float* c1pb  = W12 + 16384;                         // 128
    float* sums  = c1pb + 128;                          // 128*64
    float* cntp  = sums + NGRAPH * 64;                  // 128
    int*   cnt   = (int*)(cntp + NGRAPH);               // N
    int*   row_start = cnt + N;                         // N+1
    int*   cursor    = row_start + N + 1;               // N
    int*   part      = cursor + N;                      // 256
    int*   col       = part + 256;                      // E
    unsigned short* h2b = h1b;
    float* out2  = out1;

    // fused weight + pre-aggregation bias
    k_w12<<<129, 128, 0, stream>>>(lin1_w, lin1_b, conv1_w, W12, c1pb);

    // CSR build (XCD-localized count/fill)
    k_zeroi<<<(N + 255) / 256, 256, 0, stream>>>(cnt, N);
    k_count<<<512, 256, 0, stream>>>(dst, cnt, E, N);
    k_dis<<<(N + 255) / 256, 256, 0, stream>>>(cnt, dis, N);
    const int scanB = (N + SCAN_CHUNK - 1) / SCAN_CHUNK;
    k_scan_part<<<scanB, 256, 0, stream>>>(cnt, part, N);
    k_scan_mid<<<1, 256, 0, stream>>>(part, row_start, scanB, N);
    k_scan_fin<<<scanB, 256, 0, stream>>>(cnt, part, row_start, cursor, N);
    k_fill<<<512, 256, 0, stream>>>(src, dst, cursor, col, E, N);

    // h1b = bf16(x @ W12 + c1pb)
    const int gemmGrid = (N + 63) / 64;
    k_gemm<128, false><<<gemmGrid, 256, 0, stream>>>(x, W12, c1pb, nullptr, h1b, N);

    // conv1 aggregation: out1 = fp32 gather of bf16 h1b
    k_gather<128><<<((size_t)N * 16 + 255) / 256, 256, 0, stream>>>(h1b, row_start, col, dis, conv1_b, out1, N);

    // h2b = bf16(relu(dropout(out1)) @ conv2_w)
    k_gemm<64, true><<<gemmGrid, 256, 0, stream>>>(out1, conv2_w, nullptr, drop_u, h2b, N);

    // conv2 aggregation: out2 = fp32 gather of bf16 h2b
    k_gather<64><<<((size_t)N * 8 + 255) / 256, 256, 0, stream>>>(h2b, row_start, col, dis, conv2_b, out2, N);

    // pooled mean + classifier
    k_zero<<<(NGRAPH * 64 + NGRAPH + 255) / 256, 256, 0, stream>>>(sums, NGRAPH * 64 + NGRAPH);
    k_pool<<<128, 256, 0, stream>>>(out2, batch, sums, cntp, N);
    k_final<<<NGRAPH, 64, 0, stream>>>(sums, cntp, lin2_w, lin2_b, out);
}

// Round 6
// 554.360 us; speedup vs baseline: 8.0418x; 1.0867x over previous
//
#include <hip/hip_runtime.h>
#include <hip/hip_bf16.h>

// Problem constants (fixed by the reference file)
#define DIN   128
#define HID2  64
#define NCLS  10
#define NGRAPH 128
#define SCAN_CHUNK 1024

typedef __attribute__((ext_vector_type(8))) short bf16x8;
typedef __attribute__((ext_vector_type(4))) float f32x4;

__device__ __forceinline__ void atomAddF(float* p, float v) {
    unsafeAtomicAdd(p, v);
}

// float -> bf16 (round-to-nearest-even), finite inputs
__device__ __forceinline__ unsigned short f2bf(float f) {
    unsigned int u = __float_as_uint(f);
    u += 0x7fffu + ((u >> 16) & 1u);
    return (unsigned short)(u >> 16);
}

// ---------- K0: W12 = lin1_w @ conv1_w ; c1preb = lin1_b @ conv1_w ----------
__global__ __launch_bounds__(128) void k_w12(const float* __restrict__ lw,
                                             const float* __restrict__ lb,
                                             const float* __restrict__ cw,
                                             float* __restrict__ W12,
                                             float* __restrict__ c1preb) {
    int i = blockIdx.x, j = threadIdx.x;
    const float* arow = (i < 128) ? (lw + i * 128) : lb;
    float acc = 0.f;
#pragma unroll 8
    for (int k = 0; k < 128; ++k) acc += arow[k] * cw[k * 128 + j];
    if (i < 128) W12[i * 128 + j] = acc;
    else         c1preb[j] = acc;
}

// ---------- CSR build (XCD-localized, nt streaming reads) ----------
__global__ __launch_bounds__(256) void k_zeroi(int* p, int n) {
    int i = blockIdx.x * 256 + threadIdx.x;
    if (i < n) p[i] = 0;
}
__global__ __launch_bounds__(256) void k_zero(float* p, int n) {
    int i = blockIdx.x * 256 + threadIdx.x;
    if (i < n) p[i] = 0.0f;
}

// Partitioned histogram; dst read non-temporally so the streaming pass does not
// evict the hot cnt slice from the XCD's L2.
__global__ __launch_bounds__(256) void k_count(const int* __restrict__ dst,
                                               int* __restrict__ cnt, int E, int N) {
    const int grp = blockIdx.x & 7;
    const int chunk = (N + 7) / 8;
    const int lo = grp * chunk, hi = min(N, lo + chunk);
    const int nb = gridDim.x >> 3;
    const int bi = blockIdx.x >> 3;
    for (int e = bi * 256 + threadIdx.x; e < E; e += nb * 256) {
        int d = __builtin_nontemporal_load(dst + e);
        if (d >= lo && d < hi) atomicAdd(&cnt[d], 1);
    }
}
__global__ __launch_bounds__(256) void k_dis(const int* __restrict__ cnt, float* dis, int n) {
    int i = blockIdx.x * 256 + threadIdx.x;
    if (i < n) dis[i] = rsqrtf((float)(cnt[i] + 1));
}

// --- 3-phase parallel exclusive scan ---
__global__ __launch_bounds__(256) void k_scan_part(const int* __restrict__ cnt,
                                                   int* __restrict__ part, int n) {
    int base = blockIdx.x * SCAN_CHUNK + threadIdx.x * 4;
    int s = 0;
#pragma unroll
    for (int j = 0; j < 4; ++j) { int i = base + j; if (i < n) s += cnt[i]; }
#pragma unroll
    for (int o = 32; o > 0; o >>= 1) s += __shfl_down(s, o);
    __shared__ int wsum[4];
    if ((threadIdx.x & 63) == 0) wsum[threadIdx.x >> 6] = s;
    __syncthreads();
    if (threadIdx.x == 0) part[blockIdx.x] = wsum[0] + wsum[1] + wsum[2] + wsum[3];
}
__global__ __launch_bounds__(256) void k_scan_mid(int* __restrict__ part,
                                                  int* __restrict__ row_start,
                                                  int B, int n) {
    __shared__ int sh[256];
    int t = threadIdx.x;
    int v = (t < B) ? part[t] : 0;
    sh[t] = v;
    __syncthreads();
    for (int off = 1; off < 256; off <<= 1) {
        int u = (t >= off) ? sh[t - off] : 0;
        __syncthreads();
        sh[t] += u;
        __syncthreads();
    }
    if (t < B) part[t] = sh[t] - v;
    if (t == 255) row_start[n] = sh[255];
}
__global__ __launch_bounds__(256) void k_scan_fin(const int* __restrict__ cnt,
                                                  const int* __restrict__ part,
                                                  int* __restrict__ row_start,
                                                  int* __restrict__ cursor, int n) {
    __shared__ int sh[256];
    int t = threadIdx.x;
    int base = blockIdx.x * SCAN_CHUNK + t * 4;
    int c[4]; int s = 0;
#pragma unroll
    for (int j = 0; j < 4; ++j) { int i = base + j; c[j] = (i < n) ? cnt[i] : 0; s += c[j]; }
    sh[t] = s;
    __syncthreads();
    for (int off = 1; off < 256; off <<= 1) {
        int u = (t >= off) ? sh[t - off] : 0;
        __syncthreads();
        sh[t] += u;
        __syncthreads();
    }
    int excl = part[blockIdx.x] + sh[t] - s;
#pragma unroll
    for (int j = 0; j < 4; ++j) {
        int i = base + j;
        if (i < n) { row_start[i] = excl; cursor[i] = excl; }
        excl += c[j];
    }
}

// Partitioned fill; dst read nt so col/cursor slices stay resident in L2.
__global__ __launch_bounds__(256) void k_fill(const int* __restrict__ src,
                                              const int* __restrict__ dst,
                                              int* __restrict__ cursor,
                                              int* __restrict__ col, int E, int N) {
    const int grp = blockIdx.x & 7;
    const int chunk = (N + 7) / 8;
    const int lo = grp * chunk, hi = min(N, lo + chunk);
    const int nb = gridDim.x >> 3;
    const int bi = blockIdx.x >> 3;
    for (int e = bi * 256 + threadIdx.x; e < E; e += nb * 256) {
        int d = __builtin_nontemporal_load(dst + e);
        if (d >= lo && d < hi) {
            int pos = atomicAdd(&cursor[d], 1);
            col[pos] = src[e];
        }
    }
}

// ---------- MFMA bf16 GEMM: out[M x NCOL] = bf16(f(A[M x 128]) @ W[128 x NCOL] + bias) ----------
// A fp32 (optionally dropout+relu via du), W fp32; both converted to bf16 in LDS.
// Layouts (gfx950, 16x16x32): A/B frag [m|n = lane&15][k = quad*8+j], C/D row=quad*4+reg, col=lane&15.
template <int NCOL, bool MASK>
__global__ __launch_bounds__(256) void k_gemm_mfma(const float* __restrict__ A,
                                                   const float* __restrict__ W,
                                                   const float* __restrict__ bias,
                                                   const float* __restrict__ du,
                                                   unsigned short* __restrict__ out, int M) {
    constexpr int KP = 136;   // padded k-stride (bf16 elems); 272B row stride -> only 2-way bank aliasing
    __shared__ unsigned short As[64 * KP];
    __shared__ unsigned short Wt[NCOL * KP];

    const int tid = threadIdx.x;
    const int row0 = blockIdx.x * 64;

    // stage A tile: 64 rows x 128 k, fp32 -> bf16 (2048 float4)
    for (int f = tid; f < 2048; f += 256) {
        int r = f >> 5, c4 = f & 31;
        int gr = row0 + r;
        float4 v = make_float4(0.f, 0.f, 0.f, 0.f);
        if (gr < M) {
            v = *(const float4*)(A + (size_t)gr * 128 + c4 * 4);
            if (MASK) {
                float4 u = *(const float4*)(du + (size_t)gr * 128 + c4 * 4);
                v.x = (u.x >= 0.5f) ? 2.f * fmaxf(v.x, 0.f) : 0.f;
                v.y = (u.y >= 0.5f) ? 2.f * fmaxf(v.y, 0.f) : 0.f;
                v.z = (u.z >= 0.5f) ? 2.f * fmaxf(v.z, 0.f) : 0.f;
                v.w = (u.w >= 0.5f) ? 2.f * fmaxf(v.w, 0.f) : 0.f;
            }
        }
        ushort4 b;
        b.x = f2bf(v.x); b.y = f2bf(v.y); b.z = f2bf(v.z); b.w = f2bf(v.w);
        *(ushort4*)(&As[r * KP + c4 * 4]) = b;
    }
    // stage W transposed: Wt[n][k], fp32 -> bf16 (32*NCOL float4)
    for (int f = tid; f < 32 * NCOL; f += 256) {
        int k = f / (NCOL / 4), n4 = f % (NCOL / 4);
        float4 v = *(const float4*)(W + (size_t)k * NCOL + n4 * 4);
        Wt[(n4 * 4 + 0) * KP + k] = f2bf(v.x);
        Wt[(n4 * 4 + 1) * KP + k] = f2bf(v.y);
        Wt[(n4 * 4 + 2) * KP + k] = f2bf(v.z);
        Wt[(n4 * 4 + 3) * KP + k] = f2bf(v.w);
    }
    __syncthreads();

    const int wave = tid >> 6, lane = tid & 63;
    const int quad = lane >> 4, l16 = lane & 15;
    constexpr int CT = (NCOL == 128) ? 2 : 1;    // 16-col tiles per wave
    const int col0 = wave * 16 * CT;

    f32x4 acc[4][CT];
#pragma unroll
    for (int rt = 0; rt < 4; ++rt)
#pragma unroll
        for (int ct = 0; ct < CT; ++ct) acc[rt][ct] = 0.f;

#pragma unroll
    for (int ks = 0; ks < 4; ++ks) {
        const int kbase = ks * 32 + quad * 8;
        bf16x8 bfr[CT];
#pragma unroll
        for (int ct = 0; ct < CT; ++ct)
            bfr[ct] = *(const bf16x8*)(&Wt[(col0 + ct * 16 + l16) * KP + kbase]);
#pragma unroll
        for (int rt = 0; rt < 4; ++rt) {
            bf16x8 afr = *(const bf16x8*)(&As[(rt * 16 + l16) * KP + kbase]);
#pragma unroll
            for (int ct = 0; ct < CT; ++ct)
                acc[rt][ct] = __builtin_amdgcn_mfma_f32_16x16x32_bf16(afr, bfr[ct], acc[rt][ct], 0, 0, 0);
        }
    }

    // epilogue: add bias, cvt bf16, store
#pragma unroll
    for (int rt = 0; rt < 4; ++rt)
#pragma unroll
        for (int ct = 0; ct < CT; ++ct) {
            const int c = col0 + ct * 16 + l16;
            const float bv = bias ? bias[c] : 0.f;
#pragma unroll
            for (int reg = 0; reg < 4; ++reg) {
                const int gr = row0 + rt * 16 + quad * 4 + reg;
                if (gr < M) out[(size_t)gr * NCOL + c] = f2bf(acc[rt][ct][reg] + bv);
            }
        }
}

// ---------- CSR gather (bf16 input rows, fp32 accumulate+output) ----------
__device__ __forceinline__ void bfacc(uint4 v, float d, float* acc) {
    acc[0] = fmaf(d, __uint_as_float(v.x << 16),        acc[0]);
    acc[1] = fmaf(d, __uint_as_float(v.x & 0xffff0000u), acc[1]);
    acc[2] = fmaf(d, __uint_as_float(v.y << 16),        acc[2]);
    acc[3] = fmaf(d, __uint_as_float(v.y & 0xffff0000u), acc[3]);
    acc[4] = fmaf(d, __uint_as_float(v.z << 16),        acc[4]);
    acc[5] = fmaf(d, __uint_as_float(v.z & 0xffff0000u), acc[5]);
    acc[6] = fmaf(d, __uint_as_float(v.w << 16),        acc[6]);
    acc[7] = fmaf(d, __uint_as_float(v.w & 0xffff0000u), acc[7]);
}

template <int NCOL>
__global__ __launch_bounds__(256) void k_gather(const unsigned short* __restrict__ h,
                                                const int* __restrict__ row_start,
                                                const int* __restrict__ col,
                                                const float* __restrict__ dis,
                                                const float* __restrict__ bias,
                                                float* __restrict__ out, int n) {
    constexpr int LPN = NCOL / 8;
    const int node = (blockIdx.x * 256 + threadIdx.x) / LPN;
    const int l = threadIdx.x % LPN;
    if (node >= n) return;
    const int coff = l * 8;

    const float dn = dis[node];
    float acc[8];
    {
        uint4 v = *(const uint4*)(h + (size_t)node * NCOL + coff);
#pragma unroll
        for (int q = 0; q < 8; ++q) acc[q] = 0.f;
        bfacc(v, dn, acc);
    }

    const int beg = row_start[node], end = row_start[node + 1];
    int j = beg;
    for (; j + 1 < end; j += 2) {
        const int s0 = col[j], s1 = col[j + 1];
        const float d0 = dis[s0], d1 = dis[s1];
        const uint4 v0 = *(const uint4*)(h + (size_t)s0 * NCOL + coff);
        const uint4 v1 = *(const uint4*)(h + (size_t)s1 * NCOL + coff);
        bfacc(v0, d0, acc);
        bfacc(v1, d1, acc);
    }
    if (j < end) {
        const int s0 = col[j];
        const float d0 = dis[s0];
        const uint4 v0 = *(const uint4*)(h + (size_t)s0 * NCOL + coff);
        bfacc(v0, d0, acc);
    }

    float4 r0, r1;
    const float4 b0 = *(const float4*)(bias + coff);
    const float4 b1 = *(const float4*)(bias + coff + 4);
    r0.x = fmaf(dn, acc[0], b0.x); r0.y = fmaf(dn, acc[1], b0.y);
    r0.z = fmaf(dn, acc[2], b0.z); r0.w = fmaf(dn, acc[3], b0.w);
    r1.x = fmaf(dn, acc[4], b1.x); r1.y = fmaf(dn, acc[5], b1.y);
    r1.z = fmaf(dn, acc[6], b1.z); r1.w = fmaf(dn, acc[7], b1.w);
    float* o = out + (size_t)node * NCOL + coff;
    *(float4*)(o) = r0;
    *(float4*)(o + 4) = r1;
}

// ---------- pooling ----------
__global__ __launch_bounds__(256) void k_pool(const float* __restrict__ h,
                                              const int* __restrict__ batch,
                                              float* __restrict__ sums,
                                              float* __restrict__ cnt,
                                              int n) {
    int gid = (blockIdx.x * 256 + threadIdx.x) / 64;
    int f = threadIdx.x % 64;
    int ngroups = gridDim.x * 4;
    int per = (n + ngroups - 1) / ngroups;
    int start = gid * per;
    int end = min(n, start + per);
    if (start >= end) return;
    int cg = batch[start];
    float acc = 0.f;
    int count = 0;
    for (int i = start; i < end; ++i) {
        int b = batch[i];
        if (b != cg) {
            atomAddF(&sums[cg * 64 + f], acc);
            if (f == 0) atomAddF(&cnt[cg], (float)count);
            acc = 0.f; count = 0; cg = b;
        }
        acc += h[(size_t)i * 64 + f];
        ++count;
    }
    atomAddF(&sums[cg * 64 + f], acc);
    if (f == 0) atomAddF(&cnt[cg], (float)count);
}

// ---------- final ----------
__global__ __launch_bounds__(64) void k_final(const float* __restrict__ sums,
                                              const float* __restrict__ cnt,
                                              const float* __restrict__ w,
                                              const float* __restrict__ b,
                                              float* __restrict__ out) {
    int g = blockIdx.x, f = threadIdx.x;
    float c = fmaxf(cnt[g], 1.0f);
    float p = sums[g * 64 + f] / c;
#pragma unroll
    for (int cls = 0; cls < NCLS; ++cls) {
        float v = p * w[f * 10 + cls];
#pragma unroll
        for (int o = 32; o > 0; o >>= 1) v += __shfl_down(v, o);
        if (f == 0) out[g * 10 + cls] = v + b[cls];
    }
}

extern "C" void kernel_launch(void* const* d_in, const int* in_sizes, int n_in,
                              void* d_out, int out_size, void* d_ws, size_t ws_size,
                              hipStream_t stream) {
    const float* x       = (const float*)d_in[0];
    const int*   ei      = (const int*)d_in[1];
    const int*   batch   = (const int*)d_in[2];
    const float* drop_u  = (const float*)d_in[4];
    const float* lin1_w  = (const float*)d_in[5];
    const float* lin1_b  = (const float*)d_in[6];
    const float* conv1_w = (const float*)d_in[7];
    const float* conv1_b = (const float*)d_in[8];
    const float* conv2_w = (const float*)d_in[9];
    const float* conv2_b = (const float*)d_in[10];
    const float* lin2_w  = (const float*)d_in[11];
    const float* lin2_b  = (const float*)d_in[12];
    float* out = (float*)d_out;

    const int N = in_sizes[0] / DIN;        // 100000
    const int E = in_sizes[1] / 2;          // 1600000
    const int* src = ei;
    const int* dst = ei + E;

    // workspace layout (float units)
    float* ws    = (float*)d_ws;
    float* out1  = ws;                                  // N*128 fp32 (reused as out2: N*64)
    unsigned short* h1b = (unsigned short*)(ws + (size_t)N * 128);  // N*128 bf16 (reused as h2b: N*64)
    float* dis   = ws + (size_t)N * 128 + (size_t)N * 64;           // N
    float* W12   = dis + N;                             // 16384
    float* c1pb  = W12 + 16384;                         // 128
    float* sums  = c1pb + 128;                          // 128*64
    float* cntp  = sums + NGRAPH * 64;                  // 128
    int*   cnt   = (int*)(cntp + NGRAPH);               // N
    int*   row_start = cnt + N;                         // N+1
    int*   cursor    = row_start + N + 1;               // N
    int*   part      = cursor + N;                      // 256
    int*   col       = part + 256;                      // E
    unsigned short* h2b = h1b;
    float* out2  = out1;

    // fused weight + pre-aggregation bias
    k_w12<<<129, 128, 0, stream>>>(lin1_w, lin1_b, conv1_w, W12, c1pb);

    // CSR build (XCD-localized count/fill, nt streaming reads)
    k_zeroi<<<(N + 255) / 256, 256, 0, stream>>>(cnt, N);
    k_count<<<2048, 256, 0, stream>>>(dst, cnt, E, N);
    k_dis<<<(N + 255) / 256, 256, 0, stream>>>(cnt, dis, N);
    const int scanB = (N + SCAN_CHUNK - 1) / SCAN_CHUNK;
    k_scan_part<<<scanB, 256, 0, stream>>>(cnt, part, N);
    k_scan_mid<<<1, 256, 0, stream>>>(part, row_start, scanB, N);
    k_scan_fin<<<scanB, 256, 0, stream>>>(cnt, part, row_start, cursor, N);
    k_fill<<<2048, 256, 0, stream>>>(src, dst, cursor, col, E, N);

    // h1b = bf16(x @ W12 + c1pb)   (MFMA)
    const int gemmGrid = (N + 63) / 64;
    k_gemm_mfma<128, false><<<gemmGrid, 256, 0, stream>>>(x, W12, c1pb, nullptr, h1b, N);

    // conv1 aggregation: out1 = fp32 gather of bf16 h1b
    k_gather<128><<<((size_t)N * 16 + 255) / 256, 256, 0, stream>>>(h1b, row_start, col, dis, conv1_b, out1, N);

    // h2b = bf16(relu(dropout(out1)) @ conv2_w)   (MFMA)
    k_gemm_mfma<64, true><<<gemmGrid, 256, 0, stream>>>(out1, conv2_w, nullptr, drop_u, h2b, N);

    // conv2 aggregation: out2 = fp32 gather of bf16 h2b
    k_gather<64><<<((size_t)N * 8 + 255) / 256, 256, 0, stream>>>(h2b, row_start, col, dis, conv2_b, out2, N);

    // pooled mean + classifier
    k_zero<<<(NGRAPH * 64 + NGRAPH + 255) / 256, 256, 0, stream>>>(sums, NGRAPH * 64 + NGRAPH);
    k_pool<<<128, 256, 0, stream>>>(out2, batch, sums, cntp, N);
    k_final<<<NGRAPH, 64, 0, stream>>>(sums, cntp, lin2_w, lin2_b, out);
}

// Round 7
// 508.245 us; speedup vs baseline: 8.7715x; 1.0907x over previous
//
#include <hip/hip_runtime.h>
#include <hip/hip_bf16.h>

// Problem constants (fixed by the reference file)
#define DIN   128
#define HID2  64
#define NCLS  10
#define NGRAPH 128
#define SCAN_CHUNK 1024

typedef __attribute__((ext_vector_type(8))) short bf16x8;
typedef __attribute__((ext_vector_type(4))) float f32x4;

__device__ __forceinline__ void atomAddF(float* p, float v) {
    unsafeAtomicAdd(p, v);
}

// float -> bf16 (round-to-nearest-even), finite inputs
__device__ __forceinline__ unsigned short f2bf(float f) {
    unsigned int u = __float_as_uint(f);
    u += 0x7fffu + ((u >> 16) & 1u);
    return (unsigned short)(u >> 16);
}

// ---------- K0: W12 = lin1_w @ conv1_w ; c1preb = lin1_b @ conv1_w ----------
__global__ __launch_bounds__(128) void k_w12(const float* __restrict__ lw,
                                             const float* __restrict__ lb,
                                             const float* __restrict__ cw,
                                             float* __restrict__ W12,
                                             float* __restrict__ c1preb) {
    int i = blockIdx.x, j = threadIdx.x;
    const float* arow = (i < 128) ? (lw + i * 128) : lb;
    float acc = 0.f;
#pragma unroll 8
    for (int k = 0; k < 128; ++k) acc += arow[k] * cw[k * 128 + j];
    if (i < 128) W12[i * 128 + j] = acc;
    else         c1preb[j] = acc;
}

// ---------- CSR build (XCD-localized, nt streaming reads) ----------
__global__ __launch_bounds__(256) void k_zeroi(int* p, int n) {
    int i = blockIdx.x * 256 + threadIdx.x;
    if (i < n) p[i] = 0;
}
__global__ __launch_bounds__(256) void k_zero(float* p, int n) {
    int i = blockIdx.x * 256 + threadIdx.x;
    if (i < n) p[i] = 0.0f;
}

__global__ __launch_bounds__(256) void k_count(const int* __restrict__ dst,
                                               int* __restrict__ cnt, int E, int N) {
    const int grp = blockIdx.x & 7;
    const int chunk = (N + 7) / 8;
    const int lo = grp * chunk, hi = min(N, lo + chunk);
    const int nb = gridDim.x >> 3;
    const int bi = blockIdx.x >> 3;
    for (int e = bi * 256 + threadIdx.x; e < E; e += nb * 256) {
        int d = __builtin_nontemporal_load(dst + e);
        if (d >= lo && d < hi) atomicAdd(&cnt[d], 1);
    }
}
__global__ __launch_bounds__(256) void k_dis(const int* __restrict__ cnt, float* dis, int n) {
    int i = blockIdx.x * 256 + threadIdx.x;
    if (i < n) dis[i] = rsqrtf((float)(cnt[i] + 1));
}

// --- 3-phase parallel exclusive scan ---
__global__ __launch_bounds__(256) void k_scan_part(const int* __restrict__ cnt,
                                                   int* __restrict__ part, int n) {
    int base = blockIdx.x * SCAN_CHUNK + threadIdx.x * 4;
    int s = 0;
#pragma unroll
    for (int j = 0; j < 4; ++j) { int i = base + j; if (i < n) s += cnt[i]; }
#pragma unroll
    for (int o = 32; o > 0; o >>= 1) s += __shfl_down(s, o);
    __shared__ int wsum[4];
    if ((threadIdx.x & 63) == 0) wsum[threadIdx.x >> 6] = s;
    __syncthreads();
    if (threadIdx.x == 0) part[blockIdx.x] = wsum[0] + wsum[1] + wsum[2] + wsum[3];
}
__global__ __launch_bounds__(256) void k_scan_mid(int* __restrict__ part,
                                                  int* __restrict__ row_start,
                                                  int B, int n) {
    __shared__ int sh[256];
    int t = threadIdx.x;
    int v = (t < B) ? part[t] : 0;
    sh[t] = v;
    __syncthreads();
    for (int off = 1; off < 256; off <<= 1) {
        int u = (t >= off) ? sh[t - off] : 0;
        __syncthreads();
        sh[t] += u;
        __syncthreads();
    }
    if (t < B) part[t] = sh[t] - v;
    if (t == 255) row_start[n] = sh[255];
}
__global__ __launch_bounds__(256) void k_scan_fin(const int* __restrict__ cnt,
                                                  const int* __restrict__ part,
                                                  int* __restrict__ row_start,
                                                  int* __restrict__ cursor, int n) {
    __shared__ int sh[256];
    int t = threadIdx.x;
    int base = blockIdx.x * SCAN_CHUNK + t * 4;
    int c[4]; int s = 0;
#pragma unroll
    for (int j = 0; j < 4; ++j) { int i = base + j; c[j] = (i < n) ? cnt[i] : 0; s += c[j]; }
    sh[t] = s;
    __syncthreads();
    for (int off = 1; off < 256; off <<= 1) {
        int u = (t >= off) ? sh[t - off] : 0;
        __syncthreads();
        sh[t] += u;
        __syncthreads();
    }
    int excl = part[blockIdx.x] + sh[t] - s;
#pragma unroll
    for (int j = 0; j < 4; ++j) {
        int i = base + j;
        if (i < n) { row_start[i] = excl; cursor[i] = excl; }
        excl += c[j];
    }
}

__global__ __launch_bounds__(256) void k_fill(const int* __restrict__ src,
                                              const int* __restrict__ dst,
                                              int* __restrict__ cursor,
                                              int* __restrict__ col, int E, int N) {
    const int grp = blockIdx.x & 7;
    const int chunk = (N + 7) / 8;
    const int lo = grp * chunk, hi = min(N, lo + chunk);
    const int nb = gridDim.x >> 3;
    const int bi = blockIdx.x >> 3;
    for (int e = bi * 256 + threadIdx.x; e < E; e += nb * 256) {
        int d = __builtin_nontemporal_load(dst + e);
        if (d >= lo && d < hi) {
            int pos = atomicAdd(&cursor[d], 1);
            col[pos] = src[e];
        }
    }
}

// ---------- MFMA bf16 GEMM: out[M x NCOL] = bf16(f(A[M x 128]) @ W[128 x NCOL] + bias) ----------
template <int NCOL, bool MASK>
__global__ __launch_bounds__(256) void k_gemm_mfma(const float* __restrict__ A,
                                                   const float* __restrict__ W,
                                                   const float* __restrict__ bias,
                                                   const float* __restrict__ du,
                                                   unsigned short* __restrict__ out, int M) {
    constexpr int KP = 136;
    __shared__ unsigned short As[64 * KP];
    __shared__ unsigned short Wt[NCOL * KP];

    const int tid = threadIdx.x;
    const int row0 = blockIdx.x * 64;

    for (int f = tid; f < 2048; f += 256) {
        int r = f >> 5, c4 = f & 31;
        int gr = row0 + r;
        float4 v = make_float4(0.f, 0.f, 0.f, 0.f);
        if (gr < M) {
            v = *(const float4*)(A + (size_t)gr * 128 + c4 * 4);
            if (MASK) {
                float4 u = *(const float4*)(du + (size_t)gr * 128 + c4 * 4);
                v.x = (u.x >= 0.5f) ? 2.f * fmaxf(v.x, 0.f) : 0.f;
                v.y = (u.y >= 0.5f) ? 2.f * fmaxf(v.y, 0.f) : 0.f;
                v.z = (u.z >= 0.5f) ? 2.f * fmaxf(v.z, 0.f) : 0.f;
                v.w = (u.w >= 0.5f) ? 2.f * fmaxf(v.w, 0.f) : 0.f;
            }
        }
        ushort4 b;
        b.x = f2bf(v.x); b.y = f2bf(v.y); b.z = f2bf(v.z); b.w = f2bf(v.w);
        *(ushort4*)(&As[r * KP + c4 * 4]) = b;
    }
    for (int f = tid; f < 32 * NCOL; f += 256) {
        int k = f / (NCOL / 4), n4 = f % (NCOL / 4);
        float4 v = *(const float4*)(W + (size_t)k * NCOL + n4 * 4);
        Wt[(n4 * 4 + 0) * KP + k] = f2bf(v.x);
        Wt[(n4 * 4 + 1) * KP + k] = f2bf(v.y);
        Wt[(n4 * 4 + 2) * KP + k] = f2bf(v.z);
        Wt[(n4 * 4 + 3) * KP + k] = f2bf(v.w);
    }
    __syncthreads();

    const int wave = tid >> 6, lane = tid & 63;
    const int quad = lane >> 4, l16 = lane & 15;
    constexpr int CT = (NCOL == 128) ? 2 : 1;
    const int col0 = wave * 16 * CT;

    f32x4 acc[4][CT];
#pragma unroll
    for (int rt = 0; rt < 4; ++rt)
#pragma unroll
        for (int ct = 0; ct < CT; ++ct) acc[rt][ct] = 0.f;

#pragma unroll
    for (int ks = 0; ks < 4; ++ks) {
        const int kbase = ks * 32 + quad * 8;
        bf16x8 bfr[CT];
#pragma unroll
        for (int ct = 0; ct < CT; ++ct)
            bfr[ct] = *(const bf16x8*)(&Wt[(col0 + ct * 16 + l16) * KP + kbase]);
#pragma unroll
        for (int rt = 0; rt < 4; ++rt) {
            bf16x8 afr = *(const bf16x8*)(&As[(rt * 16 + l16) * KP + kbase]);
#pragma unroll
            for (int ct = 0; ct < CT; ++ct)
                acc[rt][ct] = __builtin_amdgcn_mfma_f32_16x16x32_bf16(afr, bfr[ct], acc[rt][ct], 0, 0, 0);
        }
    }

#pragma unroll
    for (int rt = 0; rt < 4; ++rt)
#pragma unroll
        for (int ct = 0; ct < CT; ++ct) {
            const int c = col0 + ct * 16 + l16;
            const float bv = bias ? bias[c] : 0.f;
#pragma unroll
            for (int reg = 0; reg < 4; ++reg) {
                const int gr = row0 + rt * 16 + quad * 4 + reg;
                if (gr < M) out[(size_t)gr * NCOL + c] = f2bf(acc[rt][ct][reg] + bv);
            }
        }
}

// ---------- CSR gather (bf16 input rows, fp32 accumulate+output) ----------
__device__ __forceinline__ void bfacc(uint4 v, float d, float* acc) {
    acc[0] = fmaf(d, __uint_as_float(v.x << 16),        acc[0]);
    acc[1] = fmaf(d, __uint_as_float(v.x & 0xffff0000u), acc[1]);
    acc[2] = fmaf(d, __uint_as_float(v.y << 16),        acc[2]);
    acc[3] = fmaf(d, __uint_as_float(v.y & 0xffff0000u), acc[3]);
    acc[4] = fmaf(d, __uint_as_float(v.z << 16),        acc[4]);
    acc[5] = fmaf(d, __uint_as_float(v.z & 0xffff0000u), acc[5]);
    acc[6] = fmaf(d, __uint_as_float(v.w << 16),        acc[6]);
    acc[7] = fmaf(d, __uint_as_float(v.w & 0xffff0000u), acc[7]);
}

template <int NCOL>
__global__ __launch_bounds__(256) void k_gather(const unsigned short* __restrict__ h,
                                                const int* __restrict__ row_start,
                                                const int* __restrict__ col,
                                                const float* __restrict__ dis,
                                                const float* __restrict__ bias,
                                                float* __restrict__ out, int n) {
    constexpr int LPN = NCOL / 8;
    const int node = (blockIdx.x * 256 + threadIdx.x) / LPN;
    const int l = threadIdx.x % LPN;
    if (node >= n) return;
    const int coff = l * 8;

    const float dn = dis[node];
    float acc[8];
    {
        uint4 v = *(const uint4*)(h + (size_t)node * NCOL + coff);
#pragma unroll
        for (int q = 0; q < 8; ++q) acc[q] = 0.f;
        bfacc(v, dn, acc);
    }

    const int beg = row_start[node], end = row_start[node + 1];
    int j = beg;
    for (; j + 1 < end; j += 2) {
        const int s0 = col[j], s1 = col[j + 1];
        const float d0 = dis[s0], d1 = dis[s1];
        const uint4 v0 = *(const uint4*)(h + (size_t)s0 * NCOL + coff);
        const uint4 v1 = *(const uint4*)(h + (size_t)s1 * NCOL + coff);
        bfacc(v0, d0, acc);
        bfacc(v1, d1, acc);
    }
    if (j < end) {
        const int s0 = col[j];
        const float d0 = dis[s0];
        const uint4 v0 = *(const uint4*)(h + (size_t)s0 * NCOL + coff);
        bfacc(v0, d0, acc);
    }

    float4 r0, r1;
    const float4 b0 = *(const float4*)(bias + coff);
    const float4 b1 = *(const float4*)(bias + coff + 4);
    r0.x = fmaf(dn, acc[0], b0.x); r0.y = fmaf(dn, acc[1], b0.y);
    r0.z = fmaf(dn, acc[2], b0.z); r0.w = fmaf(dn, acc[3], b0.w);
    r1.x = fmaf(dn, acc[4], b1.x); r1.y = fmaf(dn, acc[5], b1.y);
    r1.z = fmaf(dn, acc[6], b1.z); r1.w = fmaf(dn, acc[7], b1.w);
    float* o = out + (size_t)node * NCOL + coff;
    *(float4*)(o) = r0;
    *(float4*)(o + 4) = r1;
}

// ---------- pooling: sorted-batch sequential accumulation, wide grid ----------
__global__ __launch_bounds__(256) void k_pool(const float* __restrict__ h,
                                              const int* __restrict__ batch,
                                              float* __restrict__ sums,
                                              float* __restrict__ cnt,
                                              int n) {
    int gid = (blockIdx.x * 256 + threadIdx.x) / 64;
    int f = threadIdx.x % 64;
    int ngroups = gridDim.x * 4;
    int per = (n + ngroups - 1) / ngroups;
    int start = gid * per;
    int end = min(n, start + per);
    if (start >= end) return;
    int cg = batch[start];
    float acc = 0.f;
    int count = 0;
    for (int i = start; i < end; ++i) {
        int b = batch[i];
        if (b != cg) {
            atomAddF(&sums[cg * 64 + f], acc);
            if (f == 0) atomAddF(&cnt[cg], (float)count);
            acc = 0.f; count = 0; cg = b;
        }
        acc += h[(size_t)i * 64 + f];
        ++count;
    }
    atomAddF(&sums[cg * 64 + f], acc);
    if (f == 0) atomAddF(&cnt[cg], (float)count);
}

// ---------- final ----------
__global__ __launch_bounds__(64) void k_final(const float* __restrict__ sums,
                                              const float* __restrict__ cnt,
                                              const float* __restrict__ w,
                                              const float* __restrict__ b,
                                              float* __restrict__ out) {
    int g = blockIdx.x, f = threadIdx.x;
    float c = fmaxf(cnt[g], 1.0f);
    float p = sums[g * 64 + f] / c;
#pragma unroll
    for (int cls = 0; cls < NCLS; ++cls) {
        float v = p * w[f * 10 + cls];
#pragma unroll
        for (int o = 32; o > 0; o >>= 1) v += __shfl_down(v, o);
        if (f == 0) out[g * 10 + cls] = v + b[cls];
    }
}

extern "C" void kernel_launch(void* const* d_in, const int* in_sizes, int n_in,
                              void* d_out, int out_size, void* d_ws, size_t ws_size,
                              hipStream_t stream) {
    const float* x       = (const float*)d_in[0];
    const int*   ei      = (const int*)d_in[1];
    const int*   batch   = (const int*)d_in[2];
    const float* drop_u  = (const float*)d_in[4];
    const float* lin1_w  = (const float*)d_in[5];
    const float* lin1_b  = (const float*)d_in[6];
    const float* conv1_w = (const float*)d_in[7];
    const float* conv1_b = (const float*)d_in[8];
    const float* conv2_w = (const float*)d_in[9];
    const float* conv2_b = (const float*)d_in[10];
    const float* lin2_w  = (const float*)d_in[11];
    const float* lin2_b  = (const float*)d_in[12];
    float* out = (float*)d_out;

    const int N = in_sizes[0] / DIN;        // 100000
    const int E = in_sizes[1] / 2;          // 1600000
    const int* src = ei;
    const int* dst = ei + E;

    // workspace layout (float units)
    float* ws    = (float*)d_ws;
    float* out1  = ws;                                  // N*128 fp32 (reused as out2: N*64)
    unsigned short* h1b = (unsigned short*)(ws + (size_t)N * 128);  // N*128 bf16 (reused as h2b: N*64)
    float* dis   = ws + (size_t)N * 128 + (size_t)N * 64;           // N
    float* W12   = dis + N;                             // 16384
    float* c1pb  = W12 + 16384;                         // 128
    float* sums  = c1pb + 128;                          // 128*64
    float* cntp  = sums + NGRAPH * 64;                  // 128
    int*   cnt   = (int*)(cntp + NGRAPH);               // N
    int*   row_start = cnt + N;                         // N+1
    int*   cursor    = row_start + N + 1;               // N
    int*   part      = cursor + N;                      // 256
    int*   col       = part + 256;                      // E
    unsigned short* h2b = h1b;
    float* out2  = out1;

    // fused weight + pre-aggregation bias
    k_w12<<<129, 128, 0, stream>>>(lin1_w, lin1_b, conv1_w, W12, c1pb);

    // CSR build (XCD-localized count/fill, nt streaming reads)
    k_zeroi<<<(N + 255) / 256, 256, 0, stream>>>(cnt, N);
    k_count<<<2048, 256, 0, stream>>>(dst, cnt, E, N);
    k_dis<<<(N + 255) / 256, 256, 0, stream>>>(cnt, dis, N);
    const int scanB = (N + SCAN_CHUNK - 1) / SCAN_CHUNK;
    k_scan_part<<<scanB, 256, 0, stream>>>(cnt, part, N);
    k_scan_mid<<<1, 256, 0, stream>>>(part, row_start, scanB, N);
    k_scan_fin<<<scanB, 256, 0, stream>>>(cnt, part, row_start, cursor, N);
    k_fill<<<2048, 256, 0, stream>>>(src, dst, cursor, col, E, N);

    // h1b = bf16(x @ W12 + c1pb)   (MFMA)
    const int gemmGrid = (N + 63) / 64;
    k_gemm_mfma<128, false><<<gemmGrid, 256, 0, stream>>>(x, W12, c1pb, nullptr, h1b, N);

    // conv1 aggregation: out1 = fp32 gather of bf16 h1b
    k_gather<128><<<((size_t)N * 16 + 255) / 256, 256, 0, stream>>>(h1b, row_start, col, dis, conv1_b, out1, N);

    // h2b = bf16(relu(dropout(out1)) @ conv2_w)   (MFMA)
    k_gemm_mfma<64, true><<<gemmGrid, 256, 0, stream>>>(out1, conv2_w, nullptr, drop_u, h2b, N);

    // conv2 aggregation: out2 = fp32 gather of bf16 h2b
    k_gather<64><<<((size_t)N * 8 + 255) / 256, 256, 0, stream>>>(h2b, row_start, col, dis, conv2_b, out2, N);

    // pooled mean + classifier (wide grid: 8192 groups, ~12 nodes each)
    k_zero<<<(NGRAPH * 64 + NGRAPH + 255) / 256, 256, 0, stream>>>(sums, NGRAPH * 64 + NGRAPH);
    k_pool<<<2048, 256, 0, stream>>>(out2, batch, sums, cntp, N);
    k_final<<<NGRAPH, 64, 0, stream>>>(sums, cntp, lin2_w, lin2_b, out);
}